// Round 7
// baseline (441.113 us; speedup 1.0000x reference)
//
#include <hip/hip_runtime.h>

#define N_NODES 100000
#define N_PAD   100096   // 782 blocks * 128 rows
#define N_EDGES 1600000
#define N_GRAPHS 1024
#define F_IN 74
#define HID 100

#define KP1 160   // [self 0..73 | 0 74..79 | agg 80..153 | 0 154..159]
#define KP2 224   // [self h1 0..99 | agg 100..199 | 0 200..223]

#define FBF_LD 80   // bf16 feats copy row stride (shorts), 160B rows

#define CHUNK 1024
#define NCHUNK ((N_NODES + CHUNK - 1) / CHUNK)  // 98

#define NB ((N_NODES + 255) / 256)   // 391 dst-buckets of 256 nodes
#define BIN_EPB 4096                 // edges per k_bin block
#define NBB ((N_EDGES + BIN_EPB - 1) / BIN_EPB)

typedef __attribute__((ext_vector_type(8))) short short8;
typedef __attribute__((ext_vector_type(4))) float f32x4;

__device__ __forceinline__ unsigned short f2bf(float x) {
    union { float f; unsigned u; } c; c.f = x;
    unsigned u = c.u;
    unsigned r = (u + 0x7fffu + ((u >> 16) & 1u)) >> 16;
    return (unsigned short)r;
}
__device__ __forceinline__ float bf2f(unsigned short h) {
    union { unsigned u; float f; } c; c.u = ((unsigned)h) << 16;
    return c.f;
}
__device__ __forceinline__ float blo(unsigned w) { return bf2f((unsigned short)(w & 0xffffu)); }
__device__ __forceinline__ float bhi(unsigned w) { return bf2f((unsigned short)(w >> 16)); }
__device__ __forceinline__ unsigned bpack(float a, float b) {
    return (unsigned)f2bf(a) | ((unsigned)f2bf(b) << 16);
}
__device__ __forceinline__ void nt_store8(void* p, unsigned lo, unsigned hi) {
    unsigned long long v = (unsigned long long)lo | ((unsigned long long)hi << 32);
    __builtin_nontemporal_store(v, (unsigned long long*)p);
}

// ---------------- degree histogram + scan (row_ptr) ----------------

__global__ void k_hist(const int* __restrict__ dst, int* __restrict__ degcnt) {
    int e = blockIdx.x * blockDim.x + threadIdx.x;
    if (e < N_EDGES) atomicAdd(&degcnt[dst[e]], 1);
}

__global__ void k_scan1(const int* __restrict__ deg, int* __restrict__ csum) {
    __shared__ int lds[4];
    int b = blockIdx.x, t = threadIdx.x;
    int base = b * CHUNK + t * 4;
    int s = 0;
    #pragma unroll
    for (int i = 0; i < 4; ++i) {
        int idx = base + i;
        if (idx < N_NODES) s += deg[idx];
    }
    #pragma unroll
    for (int off = 32; off; off >>= 1) s += __shfl_down(s, off, 64);
    int lane = t & 63, w = t >> 6;
    if (lane == 0) lds[w] = s;
    __syncthreads();
    if (t == 0) {
        int tot = 0;
        for (int i = 0; i < 4; ++i) tot += lds[i];
        csum[b] = tot;
    }
}

__global__ void k_scan2(int* __restrict__ csum) {
    __shared__ int lds[NCHUNK];
    int t = threadIdx.x;
    if (t < NCHUNK) lds[t] = csum[t];
    __syncthreads();
    if (t == 0) {
        int run = 0;
        for (int i = 0; i < NCHUNK; ++i) { int v = lds[i]; lds[i] = run; run += v; }
    }
    __syncthreads();
    if (t < NCHUNK) csum[t] = lds[t];
}

__global__ void k_scan3(const int* __restrict__ deg, const int* __restrict__ csum,
                        int* __restrict__ row_ptr) {
    __shared__ int wsum[4];
    int b = blockIdx.x, t = threadIdx.x, lane = t & 63, w = t >> 6;
    int base = b * CHUNK + t * 4;
    int d[4];
    int s = 0;
    #pragma unroll
    for (int i = 0; i < 4; ++i) {
        int idx = base + i;
        d[i] = (idx < N_NODES) ? deg[idx] : 0;
        s += d[i];
    }
    int inc = s;
    #pragma unroll
    for (int off = 1; off < 64; off <<= 1) {
        int v = __shfl_up(inc, off, 64);
        if (lane >= off) inc += v;
    }
    if (lane == 63) wsum[w] = inc;
    int exc = inc - s;
    __syncthreads();
    int woff = 0;
    for (int i = 0; i < w; ++i) woff += wsum[i];
    int run = csum[b] + woff + exc;
    #pragma unroll
    for (int i = 0; i < 4; ++i) {
        int idx = base + i;
        if (idx < N_NODES) row_ptr[idx] = run;
        run += d[i];
    }
    if (b == 0 && t == 0) row_ptr[N_NODES] = N_EDGES;
}

// ---------------- binned CSR fill: k_bin (edge->bucket runs) + k_scatter ----------------
// bucket b = dst>>8; packed entry = (src<<8) | (dst&255).

__global__ __launch_bounds__(256) void k_bin(const int* __restrict__ src,
                                             const int* __restrict__ dst,
                                             const int* __restrict__ row_ptr,
                                             int* __restrict__ bucket_fill,
                                             unsigned* __restrict__ bbuf) {
    __shared__ int cnt[NB];
    __shared__ int base[NB];
    __shared__ int bs[NB];
    int t = threadIdx.x;
    for (int i = t; i < NB; i += 256) {
        cnt[i] = 0;
        bs[i] = row_ptr[i << 8];
    }
    __syncthreads();
    int e0 = blockIdx.x * BIN_EPB;
    int e1 = e0 + BIN_EPB < N_EDGES ? e0 + BIN_EPB : N_EDGES;
    for (int e = e0 + t; e < e1; e += 256) {
        atomicAdd(&cnt[dst[e] >> 8], 1);
    }
    __syncthreads();
    for (int i = t; i < NB; i += 256) {
        int c = cnt[i];
        base[i] = c ? atomicAdd(&bucket_fill[i], c) : 0;
        cnt[i] = 0;
    }
    __syncthreads();
    for (int e = e0 + t; e < e1; e += 256) {
        int d = dst[e];
        int b = d >> 8;
        int pos = atomicAdd(&cnt[b], 1);
        unsigned pk = ((unsigned)src[e] << 8) | (unsigned)(d & 255);
        __builtin_nontemporal_store(pk, &bbuf[(size_t)bs[b] + base[b] + pos]);
    }
}

__global__ __launch_bounds__(256) void k_scatter(const unsigned* __restrict__ bbuf,
                                                 const int* __restrict__ row_ptr,
                                                 int* __restrict__ csr) {
    __shared__ int fc[256];
    __shared__ int rp[257];
    int b = blockIdx.x, t = threadIdx.x;
    int nstart = b << 8;
    int nend = nstart + 256 < N_NODES ? nstart + 256 : N_NODES;
    fc[t] = 0;
    if (nstart + t <= nend) rp[t] = row_ptr[nstart + t];
    if (t == 0 && nend - nstart == 256) rp[256] = row_ptr[nend];
    __syncthreads();
    int s = rp[0];
    int e = rp[nend - nstart];
    for (int i = s + t; i < e; i += 256) {
        unsigned p = bbuf[i];
        int dl = (int)(p & 255u);
        int pos = atomicAdd(&fc[dl], 1);
        csr[rp[dl] + pos] = (int)(p >> 8);
    }
}

// ---------------- feats -> bf16 padded copy [N][80], uint-packed ----------------

__global__ void k_feats_bf(const float* __restrict__ feats, short* __restrict__ fbf) {
    int idx = blockIdx.x * blockDim.x + threadIdx.x;  // uint index
    if (idx >= N_NODES * (FBF_LD / 2)) return;
    int n = idx / (FBF_LD / 2), c2 = idx - n * (FBF_LD / 2);
    int c0 = 2 * c2, c1 = 2 * c2 + 1;
    float v0 = (c0 < F_IN) ? feats[(size_t)n * F_IN + c0] : 0.f;
    float v1 = (c1 < F_IN) ? feats[(size_t)n * F_IN + c1] : 0.f;
    ((unsigned*)fbf)[idx] = bpack(v0, v1);
}

// ---------------- Weight preconvert: Wt[col][k], bf16 hi/lo ----------------
// Layer1: k<74 self; 80<=k<154 agg(Wn[k-80]); else 0.
// Layer2: k<100 self; 100<=k<200 agg(Wn[k-100]); else 0.

template <int KP, int K1, int AGG0>
__global__ void k_wconv(const float* __restrict__ Ws, const float* __restrict__ Wn,
                        short* __restrict__ Whi, short* __restrict__ Wlo) {
    int idx = blockIdx.x * blockDim.x + threadIdx.x;
    if (idx >= 112 * KP) return;
    int col = idx / KP, k = idx - col * KP;
    float v = 0.f;
    if (col < HID) {
        if (k < K1) v = Ws[k * HID + col];
        else if (k >= AGG0 && k < AGG0 + K1) v = Wn[(k - AGG0) * HID + col];
    }
    unsigned short hi = f2bf(v);
    unsigned short lo = f2bf(v - bf2f(hi));
    Whi[idx] = (short)hi;
    Wlo[idx] = (short)lo;
}

// ---------------- prep1: X1 = [self bf16 | 0 | mean-agg | 0] ----------------
// 2 edges per wave: half h in {0,1}, lane q<19 loads uint2 (8B) of fbf row.

__global__ __launch_bounds__(256) void k_prep1(const short* __restrict__ fbf,
                        const int* __restrict__ row_ptr, const int* __restrict__ csr,
                        short* __restrict__ X1) {
    int wid = threadIdx.x >> 6, lane = threadIdx.x & 63;
    int v = blockIdx.x * 4 + wid;
    if (v >= N_NODES) return;
    int h = lane >> 5, q = lane & 31;
    int s = row_ptr[v], e = row_ptr[v + 1];
    float a0 = 0.f, a1 = 0.f, a2 = 0.f, a3 = 0.f;
    if (q < 19) {
        const char* Fb = (const char*)fbf;
        int j = s;
        for (; j + 7 < e; j += 8) {
            uint2 w0 = *(const uint2*)(Fb + (size_t)csr[j + h] * (FBF_LD * 2) + q * 8);
            uint2 w1 = *(const uint2*)(Fb + (size_t)csr[j + 2 + h] * (FBF_LD * 2) + q * 8);
            uint2 w2 = *(const uint2*)(Fb + (size_t)csr[j + 4 + h] * (FBF_LD * 2) + q * 8);
            uint2 w3 = *(const uint2*)(Fb + (size_t)csr[j + 6 + h] * (FBF_LD * 2) + q * 8);
            a0 += blo(w0.x) + blo(w1.x) + blo(w2.x) + blo(w3.x);
            a1 += bhi(w0.x) + bhi(w1.x) + bhi(w2.x) + bhi(w3.x);
            a2 += blo(w0.y) + blo(w1.y) + blo(w2.y) + blo(w3.y);
            a3 += bhi(w0.y) + bhi(w1.y) + bhi(w2.y) + bhi(w3.y);
        }
        for (; j < e; j += 2) {
            int ej = j + h;
            if (ej < e) {
                uint2 w = *(const uint2*)(Fb + (size_t)csr[ej] * (FBF_LD * 2) + q * 8);
                a0 += blo(w.x); a1 += bhi(w.x); a2 += blo(w.y); a3 += bhi(w.y);
            }
        }
    }
    a0 += __shfl_xor(a0, 32, 64);
    a1 += __shfl_xor(a1, 32, 64);
    a2 += __shfl_xor(a2, 32, 64);
    a3 += __shfl_xor(a3, 32, 64);
    float inv = 1.0f / fmaxf((float)(e - s), 1.0f);
    char* Xw = (char*)X1 + (size_t)v * (KP1 * 2);          // 320B row
    const char* Fr = (const char*)fbf + (size_t)v * (FBF_LD * 2);
    if (h == 0 && q < 20) {                                 // self: bytes 0..159 (incl pad zeros)
        unsigned long long sv = *(const unsigned long long*)(Fr + q * 8);
        __builtin_nontemporal_store(sv, (unsigned long long*)(Xw + q * 8));
    }
    if (h == 1 && q < 19) {                                 // agg: shorts 80..155 = bytes 160..311
        nt_store8(Xw + 160 + q * 8, bpack(a0 * inv, a1 * inv), bpack(a2 * inv, a3 * inv));
    }
    if (h == 1 && q == 19) {                                // zeros: shorts 156..159
        nt_store8(Xw + 312, 0u, 0u);
    }
}

// ---------------- prep2: X2[:,100..223] = [mean-agg h1 | 0] ----------------
// Gathers h1 directly from X2 self cols (bytes 0..199 of each 448B row). lane q<25.

__global__ __launch_bounds__(256) void k_prep2(short* __restrict__ X2,
                        const int* __restrict__ row_ptr, const int* __restrict__ csr) {
    int wid = threadIdx.x >> 6, lane = threadIdx.x & 63;
    int v = blockIdx.x * 4 + wid;
    if (v >= N_NODES) return;
    int h = lane >> 5, q = lane & 31;
    int s = row_ptr[v], e = row_ptr[v + 1];
    float a0 = 0.f, a1 = 0.f, a2 = 0.f, a3 = 0.f;
    if (q < 25) {
        const char* Xb = (const char*)X2;
        int j = s;
        for (; j + 7 < e; j += 8) {
            uint2 w0 = *(const uint2*)(Xb + (size_t)csr[j + h] * (KP2 * 2) + q * 8);
            uint2 w1 = *(const uint2*)(Xb + (size_t)csr[j + 2 + h] * (KP2 * 2) + q * 8);
            uint2 w2 = *(const uint2*)(Xb + (size_t)csr[j + 4 + h] * (KP2 * 2) + q * 8);
            uint2 w3 = *(const uint2*)(Xb + (size_t)csr[j + 6 + h] * (KP2 * 2) + q * 8);
            a0 += blo(w0.x) + blo(w1.x) + blo(w2.x) + blo(w3.x);
            a1 += bhi(w0.x) + bhi(w1.x) + bhi(w2.x) + bhi(w3.x);
            a2 += blo(w0.y) + blo(w1.y) + blo(w2.y) + blo(w3.y);
            a3 += bhi(w0.y) + bhi(w1.y) + bhi(w2.y) + bhi(w3.y);
        }
        for (; j < e; j += 2) {
            int ej = j + h;
            if (ej < e) {
                uint2 w = *(const uint2*)(Xb + (size_t)csr[ej] * (KP2 * 2) + q * 8);
                a0 += blo(w.x); a1 += bhi(w.x); a2 += blo(w.y); a3 += bhi(w.y);
            }
        }
    }
    a0 += __shfl_xor(a0, 32, 64);
    a1 += __shfl_xor(a1, 32, 64);
    a2 += __shfl_xor(a2, 32, 64);
    a3 += __shfl_xor(a3, 32, 64);
    float inv = 1.0f / fmaxf((float)(e - s), 1.0f);
    char* Xw = (char*)X2 + (size_t)v * (KP2 * 2);           // 448B row
    if (h == 0 && q < 25) {                                  // agg: shorts 100..199 = bytes 200..399
        nt_store8(Xw + 200 + q * 8, bpack(a0 * inv, a1 * inv), bpack(a2 * inv, a3 * inv));
    }
    if (h == 1 && q < 6) {                                   // zeros: shorts 200..223
        nt_store8(Xw + 400 + q * 8, 0u, 0u);
    }
}

// ---------------- MFMA GEMM: C = relu(X @ Wt^T + bias), X bf16, W hi/lo (bf16x2) ----------------
// LAST=false: write X2 self cols (bf16, cached). LAST=true: write Hout fp32 [N,100].

template <int KP, bool LAST>
__global__ __launch_bounds__(256) void k_mfma(
    const short* __restrict__ Xhi,
    const short* __restrict__ Wthi, const short* __restrict__ Wtlo,
    const float* __restrict__ bias,
    short* __restrict__ Yhi, float* __restrict__ Hout) {
    int t = threadIdx.x;
    int wid = t >> 6, lane = t & 63;
    int quad = lane >> 4, lr = lane & 15;
    int rowbase = blockIdx.x * 128 + wid * 32;

    f32x4 acc[2][7];
    #pragma unroll
    for (int rf = 0; rf < 2; ++rf)
        #pragma unroll
        for (int n = 0; n < 7; ++n) acc[rf][n] = (f32x4){0.f, 0.f, 0.f, 0.f};

    const int NC = KP / 32;
    for (int c = 0; c < NC; ++c) {
        short8 ah[2], wh[7], wl[7];
        #pragma unroll
        for (int rf = 0; rf < 2; ++rf) {
            size_t off = (size_t)(rowbase + rf * 16 + lr) * KP + c * 32 + quad * 8;
            ah[rf] = *(const short8*)(Xhi + off);
        }
        #pragma unroll
        for (int n = 0; n < 7; ++n) {
            size_t off = (size_t)(n * 16 + lr) * KP + c * 32 + quad * 8;
            wh[n] = *(const short8*)(Wthi + off);
            wl[n] = *(const short8*)(Wtlo + off);
        }
        #pragma unroll
        for (int rf = 0; rf < 2; ++rf)
            #pragma unroll
            for (int n = 0; n < 7; ++n) {
                acc[rf][n] = __builtin_amdgcn_mfma_f32_16x16x32_bf16(ah[rf], wh[n], acc[rf][n], 0, 0, 0);
                acc[rf][n] = __builtin_amdgcn_mfma_f32_16x16x32_bf16(ah[rf], wl[n], acc[rf][n], 0, 0, 0);
            }
    }

    #pragma unroll
    for (int rf = 0; rf < 2; ++rf) {
        #pragma unroll
        for (int n = 0; n < 7; ++n) {
            int col = n * 16 + lr;
            if (col < HID) {
                float bv = bias[col];
                #pragma unroll
                for (int r = 0; r < 4; ++r) {
                    int row = rowbase + rf * 16 + quad * 4 + r;
                    if (row < N_NODES) {
                        float v = fmaxf(acc[rf][n][r] + bv, 0.f);
                        if (LAST) {
                            Hout[(size_t)row * HID + col] = v;
                        } else {
                            Yhi[(size_t)row * KP2 + col] = (short)f2bf(v);
                        }
                    }
                }
            }
        }
    }
}

// ---------------- Collapsed predictor head: w_eff[200], b_eff ----------------

__global__ void k_weff(const float* __restrict__ Wp1, const float* __restrict__ bp1,
                       const float* __restrict__ Wp2, const float* __restrict__ bp2,
                       float* __restrict__ weff) {
    int t = threadIdx.x;
    if (t < 200) {
        float s = 0.f;
        for (int k = 0; k < 64; ++k) s += Wp1[t * 64 + k] * Wp2[k];
        weff[t] = s;
    } else if (t == 200) {
        float s = bp2[0];
        for (int k = 0; k < 64; ++k) s += bp1[k] * Wp2[k];
        weff[200] = s;
    }
}

// ---------------- Readout: per-graph weighted sum + max, fused head ----------------

__global__ __launch_bounds__(128) void k_readout(
    const float* __restrict__ h, const int* __restrict__ graph_ids,
    const float* __restrict__ w_atom, const float* __restrict__ b_atom,
    const float* __restrict__ weff, float* __restrict__ out) {
    int g = blockIdx.x;
    int t = threadIdx.x, lane = t & 63, w = t >> 6;

    int s_, e_;
    {
        int l = 0, r = N_NODES;
        while (l < r) { int m = (l + r) >> 1; if (graph_ids[m] < g) l = m + 1; else r = m; }
        s_ = l;
        l = s_; r = N_NODES;
        while (l < r) { int m = (l + r) >> 1; if (graph_ids[m] < g + 1) l = m + 1; else r = m; }
        e_ = l;
    }

    float ba = b_atom[0];
    float wa0 = w_atom[lane];
    float wa1 = (lane < HID - 64) ? w_atom[lane + 64] : 0.f;
    float sum0 = 0.f, sum1 = 0.f, mx0 = 0.f, mx1 = 0.f;  // h >= 0 (relu)
    for (int i = s_ + w; i < e_; i += 2) {
        const float* r = h + (size_t)i * HID;
        float v0 = r[lane];
        float v1 = (lane < HID - 64) ? r[lane + 64] : 0.f;
        float p = v0 * wa0 + v1 * wa1;
        #pragma unroll
        for (int off = 32; off; off >>= 1) p += __shfl_xor(p, off, 64);
        float wt = 1.f / (1.f + __expf(-(p + ba)));
        sum0 += v0 * wt;
        sum1 += v1 * wt;
        mx0 = fmaxf(mx0, v0);
        mx1 = fmaxf(mx1, v1);
    }

    __shared__ float ssum[2][HID];
    __shared__ float smx[2][HID];
    ssum[w][lane] = sum0;
    smx[w][lane] = mx0;
    if (lane < HID - 64) {
        ssum[w][lane + 64] = sum1;
        smx[w][lane + 64] = mx1;
    }
    __syncthreads();

    float contrib = 0.f;
    if (t < HID) {
        float sumf = ssum[0][t] + ssum[1][t];
        float mxf = fmaxf(smx[0][t], smx[1][t]);
        contrib = sumf * weff[t] + mxf * weff[HID + t];
    }
    #pragma unroll
    for (int off = 32; off; off >>= 1) contrib += __shfl_xor(contrib, off, 64);
    __shared__ float red[2];
    if (lane == 0) red[w] = contrib;
    __syncthreads();
    if (t == 0) out[g] = red[0] + red[1] + weff[200];
}

// ---------------- launch ----------------

extern "C" void kernel_launch(void* const* d_in, const int* in_sizes, int n_in,
                              void* d_out, int out_size, void* d_ws, size_t ws_size,
                              hipStream_t stream) {
    const float* node_feats = (const float*)d_in[0];
    const int* src = (const int*)d_in[1];
    const int* dst = (const int*)d_in[2];
    const int* gid = (const int*)d_in[3];
    const float* Ws1 = (const float*)d_in[5];
    const float* Wn1 = (const float*)d_in[6];
    const float* b1 = (const float*)d_in[7];
    const float* Ws2 = (const float*)d_in[8];
    const float* Wn2 = (const float*)d_in[9];
    const float* b2 = (const float*)d_in[10];
    const float* w_atom = (const float*)d_in[11];
    const float* b_atom = (const float*)d_in[12];
    const float* Wp1 = (const float*)d_in[13];
    const float* bp1 = (const float*)d_in[14];
    const float* Wp2 = (const float*)d_in[15];
    const float* bp2 = (const float*)d_in[16];
    float* out = (float*)d_out;

    char* ws = (char*)d_ws;
    size_t off = 0;
    auto alloc = [&](size_t bytes) -> void* {
        void* p = (void*)(ws + off);
        off += (bytes + 255) & ~(size_t)255;
        return p;
    };
    int* degcnt = (int*)alloc(N_NODES * sizeof(int));
    int* row_ptr = (int*)alloc((N_NODES + 1) * sizeof(int));
    int* csum = (int*)alloc(NCHUNK * sizeof(int));
    int* bucket_fill = (int*)alloc(NB * sizeof(int));
    int* csr = (int*)alloc((size_t)N_EDGES * sizeof(int));
    unsigned* bbuf = (unsigned*)alloc((size_t)N_EDGES * sizeof(unsigned));  // 6.4 MB
    short* X1hi = (short*)alloc((size_t)N_PAD * KP1 * sizeof(short));       // 32 MB
    short* X2hi = (short*)alloc((size_t)N_PAD * KP2 * sizeof(short));       // 44.8 MB
    float* h2 = (float*)alloc((size_t)N_NODES * HID * sizeof(float));       // 40 MB
    short* Wt1hi = (short*)alloc(112 * KP1 * sizeof(short));
    short* Wt1lo = (short*)alloc(112 * KP1 * sizeof(short));
    short* Wt2hi = (short*)alloc(112 * KP2 * sizeof(short));
    short* Wt2lo = (short*)alloc(112 * KP2 * sizeof(short));
    float* weff = (float*)alloc(256 * sizeof(float));
    // fbf (16MB) aliases X2hi (44.8MB): fbf dead after k_prep1; k_mfma1 then overwrites
    // every live row's self cols, and prep2/mfma2 only read rows < N_NODES.
    short* fbf = X2hi;

    hipMemsetAsync(degcnt, 0, N_NODES * sizeof(int), stream);
    hipMemsetAsync(bucket_fill, 0, NB * sizeof(int), stream);

    k_hist<<<(N_EDGES + 255) / 256, 256, 0, stream>>>(dst, degcnt);
    k_scan1<<<NCHUNK, 256, 0, stream>>>(degcnt, csum);
    k_scan2<<<1, 128, 0, stream>>>(csum);
    k_scan3<<<NCHUNK, 256, 0, stream>>>(degcnt, csum, row_ptr);
    k_bin<<<NBB, 256, 0, stream>>>(src, dst, row_ptr, bucket_fill, bbuf);
    k_scatter<<<NB, 256, 0, stream>>>(bbuf, row_ptr, csr);

    k_feats_bf<<<(N_NODES * (FBF_LD / 2) + 255) / 256, 256, 0, stream>>>(node_feats, fbf);
    k_wconv<KP1, F_IN, 80><<<(112 * KP1 + 255) / 256, 256, 0, stream>>>(Ws1, Wn1, Wt1hi, Wt1lo);
    k_wconv<KP2, HID, 100><<<(112 * KP2 + 255) / 256, 256, 0, stream>>>(Ws2, Wn2, Wt2hi, Wt2lo);

    k_prep1<<<(N_NODES + 3) / 4, 256, 0, stream>>>(fbf, row_ptr, csr, X1hi);
    k_mfma<KP1, false><<<N_PAD / 128, 256, 0, stream>>>(X1hi, Wt1hi, Wt1lo, b1, X2hi, nullptr);
    k_prep2<<<(N_NODES + 3) / 4, 256, 0, stream>>>(X2hi, row_ptr, csr);
    k_mfma<KP2, true><<<N_PAD / 128, 256, 0, stream>>>(X2hi, Wt2hi, Wt2lo, b2, nullptr, h2);

    k_weff<<<1, 256, 0, stream>>>(Wp1, bp1, Wp2, bp2, weff);
    k_readout<<<N_GRAPHS, 128, 0, stream>>>(h2, gid, w_atom, b_atom, weff, out);
}

// Round 8
// 387.060 us; speedup vs baseline: 1.1397x; 1.1397x over previous
//
#include <hip/hip_runtime.h>

#define N_NODES 100000
#define N_PAD   100096   // 782 blocks * 128 rows
#define N_EDGES 1600000
#define N_GRAPHS 1024
#define F_IN 74
#define HID 100

#define KP1 160   // [self 0..73 | 0 74..79 | agg 80..153 | 0 154..159]
#define KP2 224   // [self h1 0..99 | agg 100..199 | 0 200..223]

#define FBF_LD 80   // bf16 feats copy row stride (shorts), 160B rows
#define H1C_LD 128  // bf16 h1 compact copy row stride (shorts), 256B rows

#define CHUNK 1024
#define NCHUNK ((N_NODES + CHUNK - 1) / CHUNK)  // 98

#define NB ((N_NODES + 255) / 256)   // 391 dst-buckets of 256 nodes
#define BIN_EPB 4096                 // edges per k_bin block
#define NBB ((N_EDGES + BIN_EPB - 1) / BIN_EPB)

typedef __attribute__((ext_vector_type(8))) short short8;
typedef __attribute__((ext_vector_type(4))) float f32x4;

__device__ __forceinline__ unsigned short f2bf(float x) {
    union { float f; unsigned u; } c; c.f = x;
    unsigned u = c.u;
    unsigned r = (u + 0x7fffu + ((u >> 16) & 1u)) >> 16;
    return (unsigned short)r;
}
__device__ __forceinline__ float bf2f(unsigned short h) {
    union { unsigned u; float f; } c; c.u = ((unsigned)h) << 16;
    return c.f;
}
__device__ __forceinline__ float blo(unsigned w) { return bf2f((unsigned short)(w & 0xffffu)); }
__device__ __forceinline__ float bhi(unsigned w) { return bf2f((unsigned short)(w >> 16)); }
__device__ __forceinline__ unsigned bpack(float a, float b) {
    return (unsigned)f2bf(a) | ((unsigned)f2bf(b) << 16);
}
__device__ __forceinline__ void store8(void* p, unsigned lo, unsigned hi) {
    unsigned long long v = (unsigned long long)lo | ((unsigned long long)hi << 32);
    *(unsigned long long*)p = v;
}

// ---------------- degree histogram + scan (row_ptr) ----------------

__global__ void k_hist(const int* __restrict__ dst, int* __restrict__ degcnt) {
    int e = blockIdx.x * blockDim.x + threadIdx.x;
    if (e < N_EDGES) atomicAdd(&degcnt[dst[e]], 1);
}

__global__ void k_scan1(const int* __restrict__ deg, int* __restrict__ csum) {
    __shared__ int lds[4];
    int b = blockIdx.x, t = threadIdx.x;
    int base = b * CHUNK + t * 4;
    int s = 0;
    #pragma unroll
    for (int i = 0; i < 4; ++i) {
        int idx = base + i;
        if (idx < N_NODES) s += deg[idx];
    }
    #pragma unroll
    for (int off = 32; off; off >>= 1) s += __shfl_down(s, off, 64);
    int lane = t & 63, w = t >> 6;
    if (lane == 0) lds[w] = s;
    __syncthreads();
    if (t == 0) {
        int tot = 0;
        for (int i = 0; i < 4; ++i) tot += lds[i];
        csum[b] = tot;
    }
}

__global__ void k_scan2(int* __restrict__ csum) {
    __shared__ int lds[NCHUNK];
    int t = threadIdx.x;
    if (t < NCHUNK) lds[t] = csum[t];
    __syncthreads();
    if (t == 0) {
        int run = 0;
        for (int i = 0; i < NCHUNK; ++i) { int v = lds[i]; lds[i] = run; run += v; }
    }
    __syncthreads();
    if (t < NCHUNK) csum[t] = lds[t];
}

__global__ void k_scan3(const int* __restrict__ deg, const int* __restrict__ csum,
                        int* __restrict__ row_ptr) {
    __shared__ int wsum[4];
    int b = blockIdx.x, t = threadIdx.x, lane = t & 63, w = t >> 6;
    int base = b * CHUNK + t * 4;
    int d[4];
    int s = 0;
    #pragma unroll
    for (int i = 0; i < 4; ++i) {
        int idx = base + i;
        d[i] = (idx < N_NODES) ? deg[idx] : 0;
        s += d[i];
    }
    int inc = s;
    #pragma unroll
    for (int off = 1; off < 64; off <<= 1) {
        int v = __shfl_up(inc, off, 64);
        if (lane >= off) inc += v;
    }
    if (lane == 63) wsum[w] = inc;
    int exc = inc - s;
    __syncthreads();
    int woff = 0;
    for (int i = 0; i < w; ++i) woff += wsum[i];
    int run = csum[b] + woff + exc;
    #pragma unroll
    for (int i = 0; i < 4; ++i) {
        int idx = base + i;
        if (idx < N_NODES) row_ptr[idx] = run;
        run += d[i];
    }
    if (b == 0 && t == 0) row_ptr[N_NODES] = N_EDGES;
}

// ---------------- binned CSR fill: k_bin (edge->bucket runs) + k_scatter ----------------
// bucket b = dst>>8; packed entry = (src<<8) | (dst&255).

__global__ __launch_bounds__(256) void k_bin(const int* __restrict__ src,
                                             const int* __restrict__ dst,
                                             const int* __restrict__ row_ptr,
                                             int* __restrict__ bucket_fill,
                                             unsigned* __restrict__ bbuf) {
    __shared__ int cnt[NB];
    __shared__ int base[NB];
    __shared__ int bs[NB];
    int t = threadIdx.x;
    for (int i = t; i < NB; i += 256) {
        cnt[i] = 0;
        bs[i] = row_ptr[i << 8];
    }
    __syncthreads();
    int e0 = blockIdx.x * BIN_EPB;
    int e1 = e0 + BIN_EPB < N_EDGES ? e0 + BIN_EPB : N_EDGES;
    for (int e = e0 + t; e < e1; e += 256) {
        atomicAdd(&cnt[dst[e] >> 8], 1);
    }
    __syncthreads();
    for (int i = t; i < NB; i += 256) {
        int c = cnt[i];
        base[i] = c ? atomicAdd(&bucket_fill[i], c) : 0;
        cnt[i] = 0;
    }
    __syncthreads();
    for (int e = e0 + t; e < e1; e += 256) {
        int d = dst[e];
        int b = d >> 8;
        int pos = atomicAdd(&cnt[b], 1);
        bbuf[(size_t)bs[b] + base[b] + pos] = ((unsigned)src[e] << 8) | (unsigned)(d & 255);
    }
}

__global__ __launch_bounds__(256) void k_scatter(const unsigned* __restrict__ bbuf,
                                                 const int* __restrict__ row_ptr,
                                                 int* __restrict__ csr) {
    __shared__ int fc[256];
    __shared__ int rp[257];
    int b = blockIdx.x, t = threadIdx.x;
    int nstart = b << 8;
    int nend = nstart + 256 < N_NODES ? nstart + 256 : N_NODES;
    fc[t] = 0;
    if (nstart + t <= nend) rp[t] = row_ptr[nstart + t];
    if (t == 0 && nend - nstart == 256) rp[256] = row_ptr[nend];
    __syncthreads();
    int s = rp[0];
    int e = rp[nend - nstart];
    for (int i = s + t; i < e; i += 256) {
        unsigned p = bbuf[i];
        int dl = (int)(p & 255u);
        int pos = atomicAdd(&fc[dl], 1);
        csr[rp[dl] + pos] = (int)(p >> 8);
    }
}

// ---------------- feats -> bf16 padded copy [N][80], uint-packed ----------------

__global__ void k_feats_bf(const float* __restrict__ feats, short* __restrict__ fbf) {
    int idx = blockIdx.x * blockDim.x + threadIdx.x;  // uint index
    if (idx >= N_NODES * (FBF_LD / 2)) return;
    int n = idx / (FBF_LD / 2), c2 = idx - n * (FBF_LD / 2);
    int c0 = 2 * c2, c1 = 2 * c2 + 1;
    float v0 = (c0 < F_IN) ? feats[(size_t)n * F_IN + c0] : 0.f;
    float v1 = (c1 < F_IN) ? feats[(size_t)n * F_IN + c1] : 0.f;
    ((unsigned*)fbf)[idx] = bpack(v0, v1);
}

// ---------------- Weight preconvert: Wt[col][k], bf16 hi/lo ----------------
// Layer1: k<74 self; 80<=k<154 agg(Wn[k-80]); else 0.
// Layer2: k<100 self; 100<=k<200 agg(Wn[k-100]); else 0.

template <int KP, int K1, int AGG0>
__global__ void k_wconv(const float* __restrict__ Ws, const float* __restrict__ Wn,
                        short* __restrict__ Whi, short* __restrict__ Wlo) {
    int idx = blockIdx.x * blockDim.x + threadIdx.x;
    if (idx >= 112 * KP) return;
    int col = idx / KP, k = idx - col * KP;
    float v = 0.f;
    if (col < HID) {
        if (k < K1) v = Ws[k * HID + col];
        else if (k >= AGG0 && k < AGG0 + K1) v = Wn[(k - AGG0) * HID + col];
    }
    unsigned short hi = f2bf(v);
    unsigned short lo = f2bf(v - bf2f(hi));
    Whi[idx] = (short)hi;
    Wlo[idx] = (short)lo;
}

// ---------------- prep1: X1 = [self bf16 | 0 | mean-agg | 0] ----------------
// 2 edges per wave: half h in {0,1}, lane q<19 loads uint2 (8B) of fbf row.

__global__ __launch_bounds__(256) void k_prep1(const short* __restrict__ fbf,
                        const int* __restrict__ row_ptr, const int* __restrict__ csr,
                        short* __restrict__ X1) {
    int wid = threadIdx.x >> 6, lane = threadIdx.x & 63;
    int v = blockIdx.x * 4 + wid;
    if (v >= N_NODES) return;
    int h = lane >> 5, q = lane & 31;
    int s = row_ptr[v], e = row_ptr[v + 1];
    float a0 = 0.f, a1 = 0.f, a2 = 0.f, a3 = 0.f;
    if (q < 19) {
        const char* Fb = (const char*)fbf;
        int j = s;
        for (; j + 7 < e; j += 8) {
            uint2 w0 = *(const uint2*)(Fb + (size_t)csr[j + h] * (FBF_LD * 2) + q * 8);
            uint2 w1 = *(const uint2*)(Fb + (size_t)csr[j + 2 + h] * (FBF_LD * 2) + q * 8);
            uint2 w2 = *(const uint2*)(Fb + (size_t)csr[j + 4 + h] * (FBF_LD * 2) + q * 8);
            uint2 w3 = *(const uint2*)(Fb + (size_t)csr[j + 6 + h] * (FBF_LD * 2) + q * 8);
            a0 += blo(w0.x) + blo(w1.x) + blo(w2.x) + blo(w3.x);
            a1 += bhi(w0.x) + bhi(w1.x) + bhi(w2.x) + bhi(w3.x);
            a2 += blo(w0.y) + blo(w1.y) + blo(w2.y) + blo(w3.y);
            a3 += bhi(w0.y) + bhi(w1.y) + bhi(w2.y) + bhi(w3.y);
        }
        for (; j < e; j += 2) {
            int ej = j + h;
            if (ej < e) {
                uint2 w = *(const uint2*)(Fb + (size_t)csr[ej] * (FBF_LD * 2) + q * 8);
                a0 += blo(w.x); a1 += bhi(w.x); a2 += blo(w.y); a3 += bhi(w.y);
            }
        }
    }
    a0 += __shfl_xor(a0, 32, 64);
    a1 += __shfl_xor(a1, 32, 64);
    a2 += __shfl_xor(a2, 32, 64);
    a3 += __shfl_xor(a3, 32, 64);
    float inv = 1.0f / fmaxf((float)(e - s), 1.0f);
    char* Xw = (char*)X1 + (size_t)v * (KP1 * 2);          // 320B row
    const char* Fr = (const char*)fbf + (size_t)v * (FBF_LD * 2);
    if (h == 0 && q < 20) {                                 // self: bytes 0..159 (incl pad zeros)
        *(unsigned long long*)(Xw + q * 8) = *(const unsigned long long*)(Fr + q * 8);
    }
    if (h == 1 && q < 19) {                                 // agg: shorts 80..155 = bytes 160..311
        store8(Xw + 160 + q * 8, bpack(a0 * inv, a1 * inv), bpack(a2 * inv, a3 * inv));
    }
    if (h == 1 && q == 19) {                                // zeros: shorts 156..159
        store8(Xw + 312, 0u, 0u);
    }
}

// ---------------- prep2: X2[:,100..223] = [mean-agg h1c | 0] ----------------
// Gathers from compact h1c [N][128] bf16 (256B rows, shorts 0..99 valid). lane q<25.

__global__ __launch_bounds__(256) void k_prep2(const short* __restrict__ h1c,
                        const int* __restrict__ row_ptr, const int* __restrict__ csr,
                        short* __restrict__ X2) {
    int wid = threadIdx.x >> 6, lane = threadIdx.x & 63;
    int v = blockIdx.x * 4 + wid;
    if (v >= N_NODES) return;
    int h = lane >> 5, q = lane & 31;
    int s = row_ptr[v], e = row_ptr[v + 1];
    float a0 = 0.f, a1 = 0.f, a2 = 0.f, a3 = 0.f;
    if (q < 25) {
        const char* Hb = (const char*)h1c;
        int j = s;
        for (; j + 7 < e; j += 8) {
            uint2 w0 = *(const uint2*)(Hb + (size_t)csr[j + h] * (H1C_LD * 2) + q * 8);
            uint2 w1 = *(const uint2*)(Hb + (size_t)csr[j + 2 + h] * (H1C_LD * 2) + q * 8);
            uint2 w2 = *(const uint2*)(Hb + (size_t)csr[j + 4 + h] * (H1C_LD * 2) + q * 8);
            uint2 w3 = *(const uint2*)(Hb + (size_t)csr[j + 6 + h] * (H1C_LD * 2) + q * 8);
            a0 += blo(w0.x) + blo(w1.x) + blo(w2.x) + blo(w3.x);
            a1 += bhi(w0.x) + bhi(w1.x) + bhi(w2.x) + bhi(w3.x);
            a2 += blo(w0.y) + blo(w1.y) + blo(w2.y) + blo(w3.y);
            a3 += bhi(w0.y) + bhi(w1.y) + bhi(w2.y) + bhi(w3.y);
        }
        for (; j < e; j += 2) {
            int ej = j + h;
            if (ej < e) {
                uint2 w = *(const uint2*)(Hb + (size_t)csr[ej] * (H1C_LD * 2) + q * 8);
                a0 += blo(w.x); a1 += bhi(w.x); a2 += blo(w.y); a3 += bhi(w.y);
            }
        }
    }
    a0 += __shfl_xor(a0, 32, 64);
    a1 += __shfl_xor(a1, 32, 64);
    a2 += __shfl_xor(a2, 32, 64);
    a3 += __shfl_xor(a3, 32, 64);
    float inv = 1.0f / fmaxf((float)(e - s), 1.0f);
    char* Xw = (char*)X2 + (size_t)v * (KP2 * 2);           // 448B row
    if (h == 0 && q < 25) {                                  // agg: shorts 100..199 = bytes 200..399
        store8(Xw + 200 + q * 8, bpack(a0 * inv, a1 * inv), bpack(a2 * inv, a3 * inv));
    }
    if (h == 1 && q < 6) {                                   // zeros: shorts 200..223
        store8(Xw + 400 + q * 8, 0u, 0u);
    }
}

// ---------------- MFMA GEMM: C = relu(X @ Wt^T + bias), X bf16, W hi/lo (bf16x2) ----------------
// LAST=false: write X2 self cols + compact h1c copy. LAST=true: write Hout fp32 [N,100].

template <int KP, bool LAST>
__global__ __launch_bounds__(256) void k_mfma(
    const short* __restrict__ Xhi,
    const short* __restrict__ Wthi, const short* __restrict__ Wtlo,
    const float* __restrict__ bias,
    short* __restrict__ Yhi, short* __restrict__ h1c, float* __restrict__ Hout) {
    int t = threadIdx.x;
    int wid = t >> 6, lane = t & 63;
    int quad = lane >> 4, lr = lane & 15;
    int rowbase = blockIdx.x * 128 + wid * 32;

    f32x4 acc[2][7];
    #pragma unroll
    for (int rf = 0; rf < 2; ++rf)
        #pragma unroll
        for (int n = 0; n < 7; ++n) acc[rf][n] = (f32x4){0.f, 0.f, 0.f, 0.f};

    const int NC = KP / 32;
    for (int c = 0; c < NC; ++c) {
        short8 ah[2], wh[7], wl[7];
        #pragma unroll
        for (int rf = 0; rf < 2; ++rf) {
            size_t off = (size_t)(rowbase + rf * 16 + lr) * KP + c * 32 + quad * 8;
            ah[rf] = *(const short8*)(Xhi + off);
        }
        #pragma unroll
        for (int n = 0; n < 7; ++n) {
            size_t off = (size_t)(n * 16 + lr) * KP + c * 32 + quad * 8;
            wh[n] = *(const short8*)(Wthi + off);
            wl[n] = *(const short8*)(Wtlo + off);
        }
        #pragma unroll
        for (int rf = 0; rf < 2; ++rf)
            #pragma unroll
            for (int n = 0; n < 7; ++n) {
                acc[rf][n] = __builtin_amdgcn_mfma_f32_16x16x32_bf16(ah[rf], wh[n], acc[rf][n], 0, 0, 0);
                acc[rf][n] = __builtin_amdgcn_mfma_f32_16x16x32_bf16(ah[rf], wl[n], acc[rf][n], 0, 0, 0);
            }
    }

    #pragma unroll
    for (int rf = 0; rf < 2; ++rf) {
        #pragma unroll
        for (int n = 0; n < 7; ++n) {
            int col = n * 16 + lr;
            if (col < HID) {
                float bv = bias[col];
                #pragma unroll
                for (int r = 0; r < 4; ++r) {
                    int row = rowbase + rf * 16 + quad * 4 + r;
                    if (row < N_NODES) {
                        float v = fmaxf(acc[rf][n][r] + bv, 0.f);
                        if (LAST) {
                            Hout[(size_t)row * HID + col] = v;
                        } else {
                            short hv = (short)f2bf(v);
                            Yhi[(size_t)row * KP2 + col] = hv;
                            h1c[(size_t)row * H1C_LD + col] = hv;
                        }
                    }
                }
            }
        }
    }
}

// ---------------- Collapsed predictor head: w_eff[200], b_eff ----------------

__global__ void k_weff(const float* __restrict__ Wp1, const float* __restrict__ bp1,
                       const float* __restrict__ Wp2, const float* __restrict__ bp2,
                       float* __restrict__ weff) {
    int t = threadIdx.x;
    if (t < 200) {
        float s = 0.f;
        for (int k = 0; k < 64; ++k) s += Wp1[t * 64 + k] * Wp2[k];
        weff[t] = s;
    } else if (t == 200) {
        float s = bp2[0];
        for (int k = 0; k < 64; ++k) s += bp1[k] * Wp2[k];
        weff[200] = s;
    }
}

// ---------------- Readout: per-graph weighted sum + max, fused head ----------------

__global__ __launch_bounds__(128) void k_readout(
    const float* __restrict__ h, const int* __restrict__ graph_ids,
    const float* __restrict__ w_atom, const float* __restrict__ b_atom,
    const float* __restrict__ weff, float* __restrict__ out) {
    int g = blockIdx.x;
    int t = threadIdx.x, lane = t & 63, w = t >> 6;

    int s_, e_;
    {
        int l = 0, r = N_NODES;
        while (l < r) { int m = (l + r) >> 1; if (graph_ids[m] < g) l = m + 1; else r = m; }
        s_ = l;
        l = s_; r = N_NODES;
        while (l < r) { int m = (l + r) >> 1; if (graph_ids[m] < g + 1) l = m + 1; else r = m; }
        e_ = l;
    }

    float ba = b_atom[0];
    float wa0 = w_atom[lane];
    float wa1 = (lane < HID - 64) ? w_atom[lane + 64] : 0.f;
    float sum0 = 0.f, sum1 = 0.f, mx0 = 0.f, mx1 = 0.f;  // h >= 0 (relu)
    for (int i = s_ + w; i < e_; i += 2) {
        const float* r = h + (size_t)i * HID;
        float v0 = r[lane];
        float v1 = (lane < HID - 64) ? r[lane + 64] : 0.f;
        float p = v0 * wa0 + v1 * wa1;
        #pragma unroll
        for (int off = 32; off; off >>= 1) p += __shfl_xor(p, off, 64);
        float wt = 1.f / (1.f + __expf(-(p + ba)));
        sum0 += v0 * wt;
        sum1 += v1 * wt;
        mx0 = fmaxf(mx0, v0);
        mx1 = fmaxf(mx1, v1);
    }

    __shared__ float ssum[2][HID];
    __shared__ float smx[2][HID];
    ssum[w][lane] = sum0;
    smx[w][lane] = mx0;
    if (lane < HID - 64) {
        ssum[w][lane + 64] = sum1;
        smx[w][lane + 64] = mx1;
    }
    __syncthreads();

    float contrib = 0.f;
    if (t < HID) {
        float sumf = ssum[0][t] + ssum[1][t];
        float mxf = fmaxf(smx[0][t], smx[1][t]);
        contrib = sumf * weff[t] + mxf * weff[HID + t];
    }
    #pragma unroll
    for (int off = 32; off; off >>= 1) contrib += __shfl_xor(contrib, off, 64);
    __shared__ float red[2];
    if (lane == 0) red[w] = contrib;
    __syncthreads();
    if (t == 0) out[g] = red[0] + red[1] + weff[200];
}

// ---------------- launch ----------------

extern "C" void kernel_launch(void* const* d_in, const int* in_sizes, int n_in,
                              void* d_out, int out_size, void* d_ws, size_t ws_size,
                              hipStream_t stream) {
    const float* node_feats = (const float*)d_in[0];
    const int* src = (const int*)d_in[1];
    const int* dst = (const int*)d_in[2];
    const int* gid = (const int*)d_in[3];
    const float* Ws1 = (const float*)d_in[5];
    const float* Wn1 = (const float*)d_in[6];
    const float* b1 = (const float*)d_in[7];
    const float* Ws2 = (const float*)d_in[8];
    const float* Wn2 = (const float*)d_in[9];
    const float* b2 = (const float*)d_in[10];
    const float* w_atom = (const float*)d_in[11];
    const float* b_atom = (const float*)d_in[12];
    const float* Wp1 = (const float*)d_in[13];
    const float* bp1 = (const float*)d_in[14];
    const float* Wp2 = (const float*)d_in[15];
    const float* bp2 = (const float*)d_in[16];
    float* out = (float*)d_out;

    char* ws = (char*)d_ws;
    size_t off = 0;
    auto alloc = [&](size_t bytes) -> void* {
        void* p = (void*)(ws + off);
        off += (bytes + 255) & ~(size_t)255;
        return p;
    };
    int* degcnt = (int*)alloc(N_NODES * sizeof(int));
    int* row_ptr = (int*)alloc((N_NODES + 1) * sizeof(int));
    int* csum = (int*)alloc(NCHUNK * sizeof(int));
    int* bucket_fill = (int*)alloc(NB * sizeof(int));
    int* csr = (int*)alloc((size_t)N_EDGES * sizeof(int));
    unsigned* bbuf = (unsigned*)alloc((size_t)N_EDGES * sizeof(unsigned));    // 6.4 MB
    short* X1hi = (short*)alloc((size_t)N_PAD * KP1 * sizeof(short));         // 32 MB
    short* X2hi = (short*)alloc((size_t)N_PAD * KP2 * sizeof(short));         // 44.8 MB
    short* h1c = (short*)alloc((size_t)N_NODES * H1C_LD * sizeof(short));     // 25.6 MB
    float* h2 = (float*)alloc((size_t)N_NODES * HID * sizeof(float));         // 40 MB
    short* Wt1hi = (short*)alloc(112 * KP1 * sizeof(short));
    short* Wt1lo = (short*)alloc(112 * KP1 * sizeof(short));
    short* Wt2hi = (short*)alloc(112 * KP2 * sizeof(short));
    short* Wt2lo = (short*)alloc(112 * KP2 * sizeof(short));
    float* weff = (float*)alloc(256 * sizeof(float));
    // fbf (16MB) aliases X2hi (44.8MB): fbf dead after k_prep1; k_mfma1 then overwrites
    // every live row's self cols; prep2/mfma2 only read rows < N_NODES.
    short* fbf = X2hi;

    hipMemsetAsync(degcnt, 0, N_NODES * sizeof(int), stream);
    hipMemsetAsync(bucket_fill, 0, NB * sizeof(int), stream);

    k_hist<<<(N_EDGES + 255) / 256, 256, 0, stream>>>(dst, degcnt);
    k_scan1<<<NCHUNK, 256, 0, stream>>>(degcnt, csum);
    k_scan2<<<1, 128, 0, stream>>>(csum);
    k_scan3<<<NCHUNK, 256, 0, stream>>>(degcnt, csum, row_ptr);
    k_bin<<<NBB, 256, 0, stream>>>(src, dst, row_ptr, bucket_fill, bbuf);
    k_scatter<<<NB, 256, 0, stream>>>(bbuf, row_ptr, csr);

    k_feats_bf<<<(N_NODES * (FBF_LD / 2) + 255) / 256, 256, 0, stream>>>(node_feats, fbf);
    k_wconv<KP1, F_IN, 80><<<(112 * KP1 + 255) / 256, 256, 0, stream>>>(Ws1, Wn1, Wt1hi, Wt1lo);
    k_wconv<KP2, HID, 100><<<(112 * KP2 + 255) / 256, 256, 0, stream>>>(Ws2, Wn2, Wt2hi, Wt2lo);

    k_prep1<<<(N_NODES + 3) / 4, 256, 0, stream>>>(fbf, row_ptr, csr, X1hi);
    k_mfma<KP1, false><<<N_PAD / 128, 256, 0, stream>>>(X1hi, Wt1hi, Wt1lo, b1, X2hi, h1c, nullptr);
    k_prep2<<<(N_NODES + 3) / 4, 256, 0, stream>>>(h1c, row_ptr, csr, X2hi);
    k_mfma<KP2, true><<<N_PAD / 128, 256, 0, stream>>>(X2hi, Wt2hi, Wt2lo, b2, nullptr, nullptr, h2);

    k_weff<<<1, 256, 0, stream>>>(Wp1, bp1, Wp2, bp2, weff);
    k_readout<<<N_GRAPHS, 128, 0, stream>>>(h2, gid, w_atom, b_atom, weff, out);
}

// Round 9
// 328.172 us; speedup vs baseline: 1.3442x; 1.1794x over previous
//
#include <hip/hip_runtime.h>

#define N_NODES 100000
#define N_PAD   100096   // 782 blocks * 128 rows
#define N_EDGES 1600000
#define N_GRAPHS 1024
#define F_IN 74
#define HID 100

#define KP1 160   // W1 layout: [self 0..73 | 0 | agg 80..153 | 0]; A from fbf(k<80)+agt(k>=80)
#define KP2 224   // [self h1 0..99 | agg 100..199 | 0 200..223]

#define FBF_LD 80   // bf16 feats rows (160B)
#define AGT_LD 80   // bf16 agg1 rows (160B)
#define H1C_LD 128  // bf16 h1 compact rows (256B)
#define H2_LD  100  // bf16 h2 rows (200B)

#define NB ((N_NODES + 255) / 256)   // 391 dst-buckets of 256 nodes
#define BIN_EPB 4096                 // edges per binning block
#define NBB ((N_EDGES + BIN_EPB - 1) / BIN_EPB)

typedef __attribute__((ext_vector_type(8))) short short8;
typedef __attribute__((ext_vector_type(4))) float f32x4;

__device__ __forceinline__ unsigned short f2bf(float x) {
    union { float f; unsigned u; } c; c.f = x;
    unsigned u = c.u;
    unsigned r = (u + 0x7fffu + ((u >> 16) & 1u)) >> 16;
    return (unsigned short)r;
}
__device__ __forceinline__ float bf2f(unsigned short h) {
    union { unsigned u; float f; } c; c.u = ((unsigned)h) << 16;
    return c.f;
}
__device__ __forceinline__ float blo(unsigned w) { return bf2f((unsigned short)(w & 0xffffu)); }
__device__ __forceinline__ float bhi(unsigned w) { return bf2f((unsigned short)(w >> 16)); }
__device__ __forceinline__ unsigned bpack(float a, float b) {
    return (unsigned)f2bf(a) | ((unsigned)f2bf(b) << 16);
}
__device__ __forceinline__ void store8(void* p, unsigned lo, unsigned hi) {
    unsigned long long v = (unsigned long long)lo | ((unsigned long long)hi << 32);
    *(unsigned long long*)p = v;
}

// ---------------- bucket count + scan ----------------

__global__ __launch_bounds__(256) void k_bcnt(const int* __restrict__ dst,
                                              int* __restrict__ bucket_cnt) {
    __shared__ int cnt[NB];
    int t = threadIdx.x;
    for (int i = t; i < NB; i += 256) cnt[i] = 0;
    __syncthreads();
    int e0 = blockIdx.x * BIN_EPB;
    int e1 = e0 + BIN_EPB < N_EDGES ? e0 + BIN_EPB : N_EDGES;
    for (int e = e0 + t; e < e1; e += 256) atomicAdd(&cnt[dst[e] >> 8], 1);
    __syncthreads();
    for (int i = t; i < NB; i += 256) {
        int c = cnt[i];
        if (c) atomicAdd(&bucket_cnt[i], c);
    }
}

__global__ void k_bscan(const int* __restrict__ bucket_cnt, int* __restrict__ bucket_base) {
    __shared__ int lds[NB + 1];
    int t = threadIdx.x;
    if (t < NB) lds[t] = bucket_cnt[t];
    __syncthreads();
    if (t == 0) {
        int run = 0;
        for (int i = 0; i < NB; ++i) { int v = lds[i]; lds[i] = run; run += v; }
        lds[NB] = run;
    }
    __syncthreads();
    if (t <= NB) bucket_base[t] = lds[t];
}

// ---------------- binned CSR fill ----------------
// bucket b = dst>>8; packed entry = (src<<8) | (dst&255).

__global__ __launch_bounds__(256) void k_bin(const int* __restrict__ src,
                                             const int* __restrict__ dst,
                                             const int* __restrict__ bucket_base,
                                             int* __restrict__ bucket_fill,
                                             unsigned* __restrict__ bbuf) {
    __shared__ int cnt[NB];
    __shared__ int base[NB];
    __shared__ int bs[NB];
    int t = threadIdx.x;
    for (int i = t; i < NB; i += 256) {
        cnt[i] = 0;
        bs[i] = bucket_base[i];
    }
    __syncthreads();
    int e0 = blockIdx.x * BIN_EPB;
    int e1 = e0 + BIN_EPB < N_EDGES ? e0 + BIN_EPB : N_EDGES;
    for (int e = e0 + t; e < e1; e += 256) {
        atomicAdd(&cnt[dst[e] >> 8], 1);
    }
    __syncthreads();
    for (int i = t; i < NB; i += 256) {
        int c = cnt[i];
        base[i] = c ? atomicAdd(&bucket_fill[i], c) : 0;
        cnt[i] = 0;
    }
    __syncthreads();
    for (int e = e0 + t; e < e1; e += 256) {
        int d = dst[e];
        int b = d >> 8;
        int pos = atomicAdd(&cnt[b], 1);
        bbuf[(size_t)bs[b] + base[b] + pos] = ((unsigned)src[e] << 8) | (unsigned)(d & 255);
    }
}

// scatter: builds row_ptr (per-node) from its bucket run, then places csr entries.

__global__ __launch_bounds__(256) void k_scatter(const unsigned* __restrict__ bbuf,
                                                 const int* __restrict__ bucket_base,
                                                 int* __restrict__ row_ptr,
                                                 int* __restrict__ csr) {
    __shared__ int fc[256];
    __shared__ int ofs[256];
    __shared__ int wsum[4];
    int b = blockIdx.x, t = threadIdx.x;
    int nstart = b << 8;
    int base = bucket_base[b], bend = bucket_base[b + 1];
    fc[t] = 0;
    __syncthreads();
    for (int i = base + t; i < bend; i += 256)
        atomicAdd(&fc[bbuf[i] & 255u], 1);
    __syncthreads();
    int d = fc[t];
    int lane = t & 63, w = t >> 6;
    int inc = d;
    #pragma unroll
    for (int o = 1; o < 64; o <<= 1) {
        int x = __shfl_up(inc, o, 64);
        if (lane >= o) inc += x;
    }
    if (lane == 63) wsum[w] = inc;
    __syncthreads();
    int woff = 0;
    for (int i = 0; i < w; ++i) woff += wsum[i];
    ofs[t] = base + woff + inc - d;
    __syncthreads();
    int node = nstart + t;
    if (node < N_NODES) row_ptr[node] = ofs[t];
    if (b == 0 && t == 0) row_ptr[N_NODES] = N_EDGES;
    fc[t] = 0;
    __syncthreads();
    for (int i = base + t; i < bend; i += 256) {
        unsigned p = bbuf[i];
        int dl = (int)(p & 255u);
        int pos = atomicAdd(&fc[dl], 1);
        csr[ofs[dl] + pos] = (int)(p >> 8);
    }
}

// ---------------- feats -> bf16 padded copy [N][80], uint-packed ----------------

__global__ void k_feats_bf(const float* __restrict__ feats, short* __restrict__ fbf) {
    int idx = blockIdx.x * blockDim.x + threadIdx.x;  // uint index
    if (idx >= N_NODES * (FBF_LD / 2)) return;
    int n = idx / (FBF_LD / 2), c2 = idx - n * (FBF_LD / 2);
    int c0 = 2 * c2, c1 = 2 * c2 + 1;
    float v0 = (c0 < F_IN) ? feats[(size_t)n * F_IN + c0] : 0.f;
    float v1 = (c1 < F_IN) ? feats[(size_t)n * F_IN + c1] : 0.f;
    ((unsigned*)fbf)[idx] = bpack(v0, v1);
}

// ---------------- Weight preconvert: Wt[col][k], bf16 hi/lo ----------------

template <int KP, int K1, int AGG0>
__global__ void k_wconv(const float* __restrict__ Ws, const float* __restrict__ Wn,
                        short* __restrict__ Whi, short* __restrict__ Wlo) {
    int idx = blockIdx.x * blockDim.x + threadIdx.x;
    if (idx >= 112 * KP) return;
    int col = idx / KP, k = idx - col * KP;
    float v = 0.f;
    if (col < HID) {
        if (k < K1) v = Ws[k * HID + col];
        else if (k >= AGG0 && k < AGG0 + K1) v = Wn[(k - AGG0) * HID + col];
    }
    unsigned short hi = f2bf(v);
    unsigned short lo = f2bf(v - bf2f(hi));
    Whi[idx] = (short)hi;
    Wlo[idx] = (short)lo;
}

// ---------------- prep1: agt[v] = mean-agg of neighbor feats (bf16, 80 cols) ----------------

__global__ __launch_bounds__(256) void k_prep1(const short* __restrict__ fbf,
                        const int* __restrict__ row_ptr, const int* __restrict__ csr,
                        short* __restrict__ agt) {
    int wid = threadIdx.x >> 6, lane = threadIdx.x & 63;
    int v = blockIdx.x * 4 + wid;
    if (v >= N_NODES) return;
    int h = lane >> 5, q = lane & 31;
    int s = row_ptr[v], e = row_ptr[v + 1];
    float a0 = 0.f, a1 = 0.f, a2 = 0.f, a3 = 0.f;
    if (q < 19) {
        const char* Fb = (const char*)fbf;
        int j = s;
        for (; j + 7 < e; j += 8) {
            uint2 w0 = *(const uint2*)(Fb + (size_t)csr[j + h] * (FBF_LD * 2) + q * 8);
            uint2 w1 = *(const uint2*)(Fb + (size_t)csr[j + 2 + h] * (FBF_LD * 2) + q * 8);
            uint2 w2 = *(const uint2*)(Fb + (size_t)csr[j + 4 + h] * (FBF_LD * 2) + q * 8);
            uint2 w3 = *(const uint2*)(Fb + (size_t)csr[j + 6 + h] * (FBF_LD * 2) + q * 8);
            a0 += blo(w0.x) + blo(w1.x) + blo(w2.x) + blo(w3.x);
            a1 += bhi(w0.x) + bhi(w1.x) + bhi(w2.x) + bhi(w3.x);
            a2 += blo(w0.y) + blo(w1.y) + blo(w2.y) + blo(w3.y);
            a3 += bhi(w0.y) + bhi(w1.y) + bhi(w2.y) + bhi(w3.y);
        }
        for (; j < e; j += 2) {
            int ej = j + h;
            if (ej < e) {
                uint2 w = *(const uint2*)(Fb + (size_t)csr[ej] * (FBF_LD * 2) + q * 8);
                a0 += blo(w.x); a1 += bhi(w.x); a2 += blo(w.y); a3 += bhi(w.y);
            }
        }
    }
    a0 += __shfl_xor(a0, 32, 64);
    a1 += __shfl_xor(a1, 32, 64);
    a2 += __shfl_xor(a2, 32, 64);
    a3 += __shfl_xor(a3, 32, 64);
    float inv = 1.0f / fmaxf((float)(e - s), 1.0f);
    if (h == 0 && q < 20) {  // shorts 4q..4q+3 (zeros for q>=19 since loads were skipped)
        store8((char*)agt + (size_t)v * (AGT_LD * 2) + q * 8,
               bpack(a0 * inv, a1 * inv), bpack(a2 * inv, a3 * inv));
    }
}

// ---------------- prep2: X2[:,100..223] = [mean-agg h1c | 0] ----------------

__global__ __launch_bounds__(256) void k_prep2(const short* __restrict__ h1c,
                        const int* __restrict__ row_ptr, const int* __restrict__ csr,
                        short* __restrict__ X2) {
    int wid = threadIdx.x >> 6, lane = threadIdx.x & 63;
    int v = blockIdx.x * 4 + wid;
    if (v >= N_NODES) return;
    int h = lane >> 5, q = lane & 31;
    int s = row_ptr[v], e = row_ptr[v + 1];
    float a0 = 0.f, a1 = 0.f, a2 = 0.f, a3 = 0.f;
    if (q < 25) {
        const char* Hb = (const char*)h1c;
        int j = s;
        for (; j + 7 < e; j += 8) {
            uint2 w0 = *(const uint2*)(Hb + (size_t)csr[j + h] * (H1C_LD * 2) + q * 8);
            uint2 w1 = *(const uint2*)(Hb + (size_t)csr[j + 2 + h] * (H1C_LD * 2) + q * 8);
            uint2 w2 = *(const uint2*)(Hb + (size_t)csr[j + 4 + h] * (H1C_LD * 2) + q * 8);
            uint2 w3 = *(const uint2*)(Hb + (size_t)csr[j + 6 + h] * (H1C_LD * 2) + q * 8);
            a0 += blo(w0.x) + blo(w1.x) + blo(w2.x) + blo(w3.x);
            a1 += bhi(w0.x) + bhi(w1.x) + bhi(w2.x) + bhi(w3.x);
            a2 += blo(w0.y) + blo(w1.y) + blo(w2.y) + blo(w3.y);
            a3 += bhi(w0.y) + bhi(w1.y) + bhi(w2.y) + bhi(w3.y);
        }
        for (; j < e; j += 2) {
            int ej = j + h;
            if (ej < e) {
                uint2 w = *(const uint2*)(Hb + (size_t)csr[ej] * (H1C_LD * 2) + q * 8);
                a0 += blo(w.x); a1 += bhi(w.x); a2 += blo(w.y); a3 += bhi(w.y);
            }
        }
    }
    a0 += __shfl_xor(a0, 32, 64);
    a1 += __shfl_xor(a1, 32, 64);
    a2 += __shfl_xor(a2, 32, 64);
    a3 += __shfl_xor(a3, 32, 64);
    float inv = 1.0f / fmaxf((float)(e - s), 1.0f);
    char* Xw = (char*)X2 + (size_t)v * (KP2 * 2);           // 448B row
    if (h == 0 && q < 25) {                                  // agg: shorts 100..199
        store8(Xw + 200 + q * 8, bpack(a0 * inv, a1 * inv), bpack(a2 * inv, a3 * inv));
    }
    if (h == 1 && q < 6) {                                   // zeros: shorts 200..223
        store8(Xw + 400 + q * 8, 0u, 0u);
    }
}

// ---------------- mfma1: h1 = relu([fbf|agt] @ Wt1^T + b1) -> X2 self + h1c ----------------

__global__ __launch_bounds__(256) void k_mfma1(
    const short* __restrict__ fbf, const short* __restrict__ agt,
    const short* __restrict__ Wthi, const short* __restrict__ Wtlo,
    const float* __restrict__ bias,
    short* __restrict__ X2, short* __restrict__ h1c) {
    int t = threadIdx.x;
    int wid = t >> 6, lane = t & 63;
    int quad = lane >> 4, lr = lane & 15;
    int rowbase = blockIdx.x * 128 + wid * 32;

    f32x4 acc[2][7];
    #pragma unroll
    for (int rf = 0; rf < 2; ++rf)
        #pragma unroll
        for (int n = 0; n < 7; ++n) acc[rf][n] = (f32x4){0.f, 0.f, 0.f, 0.f};

    #pragma unroll
    for (int c = 0; c < 5; ++c) {
        short8 ah[2], wh[7], wl[7];
        #pragma unroll
        for (int rf = 0; rf < 2; ++rf) {
            int row = rowbase + rf * 16 + lr;
            const short* p;
            if (c < 2) p = fbf + (size_t)row * FBF_LD + c * 32 + quad * 8;
            else if (c == 2) p = (quad < 2) ? fbf + (size_t)row * FBF_LD + 64 + quad * 8
                                            : agt + (size_t)row * AGT_LD + (quad - 2) * 8;
            else p = agt + (size_t)row * AGT_LD + (c - 3) * 32 + 16 + quad * 8;
            ah[rf] = *(const short8*)p;
        }
        #pragma unroll
        for (int n = 0; n < 7; ++n) {
            size_t off = (size_t)(n * 16 + lr) * KP1 + c * 32 + quad * 8;
            wh[n] = *(const short8*)(Wthi + off);
            wl[n] = *(const short8*)(Wtlo + off);
        }
        #pragma unroll
        for (int rf = 0; rf < 2; ++rf)
            #pragma unroll
            for (int n = 0; n < 7; ++n) {
                acc[rf][n] = __builtin_amdgcn_mfma_f32_16x16x32_bf16(ah[rf], wh[n], acc[rf][n], 0, 0, 0);
                acc[rf][n] = __builtin_amdgcn_mfma_f32_16x16x32_bf16(ah[rf], wl[n], acc[rf][n], 0, 0, 0);
            }
    }

    #pragma unroll
    for (int rf = 0; rf < 2; ++rf) {
        #pragma unroll
        for (int n = 0; n < 7; ++n) {
            int col = n * 16 + lr;
            if (col < HID) {
                float bv = bias[col];
                #pragma unroll
                for (int r = 0; r < 4; ++r) {
                    int row = rowbase + rf * 16 + quad * 4 + r;
                    if (row < N_NODES) {
                        float v = fmaxf(acc[rf][n][r] + bv, 0.f);
                        short hv = (short)f2bf(v);
                        X2[(size_t)row * KP2 + col] = hv;
                        h1c[(size_t)row * H1C_LD + col] = hv;
                    }
                }
            }
        }
    }
}

// ---------------- mfma2: h2 = relu(X2 @ Wt2^T + b2) -> bf16 [N][100] ----------------

__global__ __launch_bounds__(256) void k_mfma2(
    const short* __restrict__ X2,
    const short* __restrict__ Wthi, const short* __restrict__ Wtlo,
    const float* __restrict__ bias, short* __restrict__ h2c) {
    int t = threadIdx.x;
    int wid = t >> 6, lane = t & 63;
    int quad = lane >> 4, lr = lane & 15;
    int rowbase = blockIdx.x * 128 + wid * 32;

    f32x4 acc[2][7];
    #pragma unroll
    for (int rf = 0; rf < 2; ++rf)
        #pragma unroll
        for (int n = 0; n < 7; ++n) acc[rf][n] = (f32x4){0.f, 0.f, 0.f, 0.f};

    #pragma unroll
    for (int c = 0; c < 7; ++c) {
        short8 ah[2], wh[7], wl[7];
        #pragma unroll
        for (int rf = 0; rf < 2; ++rf) {
            size_t off = (size_t)(rowbase + rf * 16 + lr) * KP2 + c * 32 + quad * 8;
            ah[rf] = *(const short8*)(X2 + off);
        }
        #pragma unroll
        for (int n = 0; n < 7; ++n) {
            size_t off = (size_t)(n * 16 + lr) * KP2 + c * 32 + quad * 8;
            wh[n] = *(const short8*)(Wthi + off);
            wl[n] = *(const short8*)(Wtlo + off);
        }
        #pragma unroll
        for (int rf = 0; rf < 2; ++rf)
            #pragma unroll
            for (int n = 0; n < 7; ++n) {
                acc[rf][n] = __builtin_amdgcn_mfma_f32_16x16x32_bf16(ah[rf], wh[n], acc[rf][n], 0, 0, 0);
                acc[rf][n] = __builtin_amdgcn_mfma_f32_16x16x32_bf16(ah[rf], wl[n], acc[rf][n], 0, 0, 0);
            }
    }

    #pragma unroll
    for (int rf = 0; rf < 2; ++rf) {
        #pragma unroll
        for (int n = 0; n < 7; ++n) {
            int col = n * 16 + lr;
            if (col < HID) {
                float bv = bias[col];
                #pragma unroll
                for (int r = 0; r < 4; ++r) {
                    int row = rowbase + rf * 16 + quad * 4 + r;
                    if (row < N_NODES) {
                        float v = fmaxf(acc[rf][n][r] + bv, 0.f);
                        h2c[(size_t)row * H2_LD + col] = (short)f2bf(v);
                    }
                }
            }
        }
    }
}

// ---------------- Collapsed predictor head: w_eff[200], b_eff ----------------

__global__ void k_weff(const float* __restrict__ Wp1, const float* __restrict__ bp1,
                       const float* __restrict__ Wp2, const float* __restrict__ bp2,
                       float* __restrict__ weff) {
    int t = threadIdx.x;
    if (t < 200) {
        float s = 0.f;
        for (int k = 0; k < 64; ++k) s += Wp1[t * 64 + k] * Wp2[k];
        weff[t] = s;
    } else if (t == 200) {
        float s = bp2[0];
        for (int k = 0; k < 64; ++k) s += bp1[k] * Wp2[k];
        weff[200] = s;
    }
}

// ---------------- Readout (bf16 h2): per-graph weighted sum + max, fused head ----------------

__global__ __launch_bounds__(128) void k_readout(
    const unsigned short* __restrict__ h2c, const int* __restrict__ graph_ids,
    const float* __restrict__ w_atom, const float* __restrict__ b_atom,
    const float* __restrict__ weff, float* __restrict__ out) {
    int g = blockIdx.x;
    int t = threadIdx.x, lane = t & 63, w = t >> 6;

    int s_, e_;
    {
        int l = 0, r = N_NODES;
        while (l < r) { int m = (l + r) >> 1; if (graph_ids[m] < g) l = m + 1; else r = m; }
        s_ = l;
        l = s_; r = N_NODES;
        while (l < r) { int m = (l + r) >> 1; if (graph_ids[m] < g + 1) l = m + 1; else r = m; }
        e_ = l;
    }

    float ba = b_atom[0];
    float wa0 = w_atom[lane];
    float wa1 = (lane < HID - 64) ? w_atom[lane + 64] : 0.f;
    float sum0 = 0.f, sum1 = 0.f, mx0 = 0.f, mx1 = 0.f;  // h >= 0 (relu)
    for (int i = s_ + w; i < e_; i += 2) {
        const unsigned short* r = h2c + (size_t)i * H2_LD;
        float v0 = bf2f(r[lane]);
        float v1 = (lane < HID - 64) ? bf2f(r[lane + 64]) : 0.f;
        float p = v0 * wa0 + v1 * wa1;
        #pragma unroll
        for (int off = 32; off; off >>= 1) p += __shfl_xor(p, off, 64);
        float wt = 1.f / (1.f + __expf(-(p + ba)));
        sum0 += v0 * wt;
        sum1 += v1 * wt;
        mx0 = fmaxf(mx0, v0);
        mx1 = fmaxf(mx1, v1);
    }

    __shared__ float ssum[2][HID];
    __shared__ float smx[2][HID];
    ssum[w][lane] = sum0;
    smx[w][lane] = mx0;
    if (lane < HID - 64) {
        ssum[w][lane + 64] = sum1;
        smx[w][lane + 64] = mx1;
    }
    __syncthreads();

    float contrib = 0.f;
    if (t < HID) {
        float sumf = ssum[0][t] + ssum[1][t];
        float mxf = fmaxf(smx[0][t], smx[1][t]);
        contrib = sumf * weff[t] + mxf * weff[HID + t];
    }
    #pragma unroll
    for (int off = 32; off; off >>= 1) contrib += __shfl_xor(contrib, off, 64);
    __shared__ float red[2];
    if (lane == 0) red[w] = contrib;
    __syncthreads();
    if (t == 0) out[g] = red[0] + red[1] + weff[200];
}

// ---------------- launch ----------------

extern "C" void kernel_launch(void* const* d_in, const int* in_sizes, int n_in,
                              void* d_out, int out_size, void* d_ws, size_t ws_size,
                              hipStream_t stream) {
    const float* node_feats = (const float*)d_in[0];
    const int* src = (const int*)d_in[1];
    const int* dst = (const int*)d_in[2];
    const int* gid = (const int*)d_in[3];
    const float* Ws1 = (const float*)d_in[5];
    const float* Wn1 = (const float*)d_in[6];
    const float* b1 = (const float*)d_in[7];
    const float* Ws2 = (const float*)d_in[8];
    const float* Wn2 = (const float*)d_in[9];
    const float* b2 = (const float*)d_in[10];
    const float* w_atom = (const float*)d_in[11];
    const float* b_atom = (const float*)d_in[12];
    const float* Wp1 = (const float*)d_in[13];
    const float* bp1 = (const float*)d_in[14];
    const float* Wp2 = (const float*)d_in[15];
    const float* bp2 = (const float*)d_in[16];
    float* out = (float*)d_out;

    char* ws = (char*)d_ws;
    size_t off = 0;
    auto alloc = [&](size_t bytes) -> void* {
        void* p = (void*)(ws + off);
        off += (bytes + 255) & ~(size_t)255;
        return p;
    };
    int* row_ptr = (int*)alloc((N_NODES + 1) * sizeof(int));
    int* bucket_cnt = (int*)alloc(NB * sizeof(int));
    int* bucket_base = (int*)alloc((NB + 1) * sizeof(int));
    int* bucket_fill = (int*)alloc(NB * sizeof(int));
    int* csr = (int*)alloc((size_t)N_EDGES * sizeof(int));
    unsigned* bbuf = (unsigned*)alloc((size_t)N_EDGES * sizeof(unsigned));    // 6.4 MB
    short* fbf = (short*)alloc((size_t)N_PAD * FBF_LD * sizeof(short));       // 16 MB
    short* agt = (short*)alloc((size_t)N_PAD * AGT_LD * sizeof(short));       // 16 MB
    short* X2 = (short*)alloc((size_t)N_PAD * KP2 * sizeof(short));           // 44.8 MB
    short* h1c = (short*)alloc((size_t)N_NODES * H1C_LD * sizeof(short));     // 25.6 MB
    short* h2c = (short*)alloc((size_t)N_NODES * H2_LD * sizeof(short));      // 20 MB
    short* Wt1hi = (short*)alloc(112 * KP1 * sizeof(short));
    short* Wt1lo = (short*)alloc(112 * KP1 * sizeof(short));
    short* Wt2hi = (short*)alloc(112 * KP2 * sizeof(short));
    short* Wt2lo = (short*)alloc(112 * KP2 * sizeof(short));
    float* weff = (float*)alloc(256 * sizeof(float));

    hipMemsetAsync(bucket_cnt, 0, NB * sizeof(int), stream);
    hipMemsetAsync(bucket_fill, 0, NB * sizeof(int), stream);

    k_bcnt<<<NBB, 256, 0, stream>>>(dst, bucket_cnt);
    k_bscan<<<1, 512, 0, stream>>>(bucket_cnt, bucket_base);
    k_bin<<<NBB, 256, 0, stream>>>(src, dst, bucket_base, bucket_fill, bbuf);
    k_scatter<<<NB, 256, 0, stream>>>(bbuf, bucket_base, row_ptr, csr);

    k_feats_bf<<<(N_NODES * (FBF_LD / 2) + 255) / 256, 256, 0, stream>>>(node_feats, fbf);
    k_wconv<KP1, F_IN, 80><<<(112 * KP1 + 255) / 256, 256, 0, stream>>>(Ws1, Wn1, Wt1hi, Wt1lo);
    k_wconv<KP2, HID, 100><<<(112 * KP2 + 255) / 256, 256, 0, stream>>>(Ws2, Wn2, Wt2hi, Wt2lo);

    k_prep1<<<(N_NODES + 3) / 4, 256, 0, stream>>>(fbf, row_ptr, csr, agt);
    k_mfma1<<<N_PAD / 128, 256, 0, stream>>>(fbf, agt, Wt1hi, Wt1lo, b1, X2, h1c);
    k_prep2<<<(N_NODES + 3) / 4, 256, 0, stream>>>(h1c, row_ptr, csr, X2);
    k_mfma2<<<N_PAD / 128, 256, 0, stream>>>(X2, Wt2hi, Wt2lo, b2, h2c);

    k_weff<<<1, 256, 0, stream>>>(Wp1, bp1, Wp2, bp2, weff);
    k_readout<<<N_GRAPHS, 128, 0, stream>>>((const unsigned short*)h2c, gid, w_atom, b_atom, weff, out);
}

// Round 10
// 317.551 us; speedup vs baseline: 1.3891x; 1.0334x over previous
//
#include <hip/hip_runtime.h>

#define N_NODES 100000
#define N_PAD   100096   // 782 blocks * 128 rows
#define N_EDGES 1600000
#define N_GRAPHS 1024
#define F_IN 74
#define HID 100

#define KP1 160   // W1 layout: [self 0..73 | 0 | agg 80..153 | 0]; A from fbf(k<80)+agt(k>=80)
#define KP2 224   // [self h1 0..99 | agg 100..199 | 0 200..223]

#define FBF_LD 80    // bf16 feats rows (160B)
#define AGT_LD 80    // bf16 agg1 rows (160B)
#define H1C8_LD 128  // fp8 h1 compact rows (128B)
#define H2_LD  100   // bf16 h2 rows (200B)

#define NB ((N_NODES + 255) / 256)   // 391 dst-buckets of 256 nodes
#define BIN_EPB 4096                 // edges per binning block
#define NBB ((N_EDGES + BIN_EPB - 1) / BIN_EPB)

typedef __attribute__((ext_vector_type(8))) short short8;
typedef __attribute__((ext_vector_type(4))) float f32x4;
typedef __attribute__((ext_vector_type(2))) float f32x2;

#if defined(__has_builtin)
#if __has_builtin(__builtin_amdgcn_cvt_pk_f32_fp8) && __has_builtin(__builtin_amdgcn_cvt_pk_fp8_f32)
#define HAVE_FP8 1
#endif
#endif

__device__ __forceinline__ unsigned short f2bf(float x) {
    union { float f; unsigned u; } c; c.f = x;
    unsigned u = c.u;
    unsigned r = (u + 0x7fffu + ((u >> 16) & 1u)) >> 16;
    return (unsigned short)r;
}
__device__ __forceinline__ float bf2f(unsigned short h) {
    union { unsigned u; float f; } c; c.u = ((unsigned)h) << 16;
    return c.f;
}
__device__ __forceinline__ float blo(unsigned w) { return bf2f((unsigned short)(w & 0xffffu)); }
__device__ __forceinline__ float bhi(unsigned w) { return bf2f((unsigned short)(w >> 16)); }
__device__ __forceinline__ unsigned bpack(float a, float b) {
    return (unsigned)f2bf(a) | ((unsigned)f2bf(b) << 16);
}
__device__ __forceinline__ void store8(void* p, unsigned lo, unsigned hi) {
    unsigned long long v = (unsigned long long)lo | ((unsigned long long)hi << 32);
    *(unsigned long long*)p = v;
}

// fp8 e4m3 helpers (values >= 0 only, from relu)
__device__ __forceinline__ unsigned char enc_fp8(float v) {
#ifdef HAVE_FP8
    return (unsigned char)__builtin_amdgcn_cvt_pk_fp8_f32(v, 0.f, 0, false);
#else
    union { float f; unsigned u; } c; c.f = v;
    if (v < 0.015625f) {  // subnormal: q = round(v * 512)
        int q = (int)(v * 512.0f + 0.5f);
        return (unsigned char)(q > 7 ? 7 : q);
    }
    unsigned u = c.u;
    unsigned r = u + 0x7ffff + ((u >> 20) & 1u);
    int e = (int)(r >> 23) - 127;
    if (e > 8) return (unsigned char)0x7e;
    return (unsigned char)(((e + 7) << 3) | ((r >> 20) & 7u));
#endif
}
// decode 4 fp8 bytes -> 4 floats
__device__ __forceinline__ void dec_fp8x4(unsigned w, float& x0, float& x1, float& x2, float& x3) {
#ifdef HAVE_FP8
    f32x2 lo = __builtin_amdgcn_cvt_pk_f32_fp8((int)w, false);
    f32x2 hi = __builtin_amdgcn_cvt_pk_f32_fp8((int)w, true);
    x0 = lo.x; x1 = lo.y; x2 = hi.x; x3 = hi.y;
#else
    auto d1 = [](unsigned b) -> float {
        if (b < 8) return (float)b * 0.001953125f;  // subnormal: b * 2^-9
        union { unsigned u; float f; } c;
        c.u = ((((b >> 3) & 15u) - 7 + 127) << 23) | ((b & 7u) << 20);
        return c.f;
    };
    x0 = d1(w & 0xffu); x1 = d1((w >> 8) & 0xffu);
    x2 = d1((w >> 16) & 0xffu); x3 = d1(w >> 24);
#endif
}

// ---------------- bucket count + scan ----------------

__global__ __launch_bounds__(256) void k_bcnt(const int* __restrict__ dst,
                                              int* __restrict__ bucket_cnt) {
    __shared__ int cnt[NB];
    int t = threadIdx.x;
    for (int i = t; i < NB; i += 256) cnt[i] = 0;
    __syncthreads();
    int e0 = blockIdx.x * BIN_EPB;
    int e1 = e0 + BIN_EPB < N_EDGES ? e0 + BIN_EPB : N_EDGES;
    for (int e = e0 + t; e < e1; e += 256) atomicAdd(&cnt[dst[e] >> 8], 1);
    __syncthreads();
    for (int i = t; i < NB; i += 256) {
        int c = cnt[i];
        if (c) atomicAdd(&bucket_cnt[i], c);
    }
}

__global__ void k_bscan(const int* __restrict__ bucket_cnt, int* __restrict__ bucket_base) {
    __shared__ int lds[NB + 1];
    int t = threadIdx.x;
    if (t < NB) lds[t] = bucket_cnt[t];
    __syncthreads();
    if (t == 0) {
        int run = 0;
        for (int i = 0; i < NB; ++i) { int v = lds[i]; lds[i] = run; run += v; }
        lds[NB] = run;
    }
    __syncthreads();
    if (t <= NB) bucket_base[t] = lds[t];
}

// ---------------- binned CSR fill ----------------
// bucket b = dst>>8; packed entry = (src<<8) | (dst&255).

__global__ __launch_bounds__(256) void k_bin(const int* __restrict__ src,
                                             const int* __restrict__ dst,
                                             const int* __restrict__ bucket_base,
                                             int* __restrict__ bucket_fill,
                                             unsigned* __restrict__ bbuf) {
    __shared__ int cnt[NB];
    __shared__ int base[NB];
    __shared__ int bs[NB];
    int t = threadIdx.x;
    for (int i = t; i < NB; i += 256) {
        cnt[i] = 0;
        bs[i] = bucket_base[i];
    }
    __syncthreads();
    int e0 = blockIdx.x * BIN_EPB;
    int e1 = e0 + BIN_EPB < N_EDGES ? e0 + BIN_EPB : N_EDGES;
    for (int e = e0 + t; e < e1; e += 256) {
        atomicAdd(&cnt[dst[e] >> 8], 1);
    }
    __syncthreads();
    for (int i = t; i < NB; i += 256) {
        int c = cnt[i];
        base[i] = c ? atomicAdd(&bucket_fill[i], c) : 0;
        cnt[i] = 0;
    }
    __syncthreads();
    for (int e = e0 + t; e < e1; e += 256) {
        int d = dst[e];
        int b = d >> 8;
        int pos = atomicAdd(&cnt[b], 1);
        bbuf[(size_t)bs[b] + base[b] + pos] = ((unsigned)src[e] << 8) | (unsigned)(d & 255);
    }
}

// scatter: builds row_ptr (per-node) from its bucket run, then places csr entries.

__global__ __launch_bounds__(256) void k_scatter(const unsigned* __restrict__ bbuf,
                                                 const int* __restrict__ bucket_base,
                                                 int* __restrict__ row_ptr,
                                                 int* __restrict__ csr) {
    __shared__ int fc[256];
    __shared__ int ofs[256];
    __shared__ int wsum[4];
    int b = blockIdx.x, t = threadIdx.x;
    int nstart = b << 8;
    int base = bucket_base[b], bend = bucket_base[b + 1];
    fc[t] = 0;
    __syncthreads();
    for (int i = base + t; i < bend; i += 256)
        atomicAdd(&fc[bbuf[i] & 255u], 1);
    __syncthreads();
    int d = fc[t];
    int lane = t & 63, w = t >> 6;
    int inc = d;
    #pragma unroll
    for (int o = 1; o < 64; o <<= 1) {
        int x = __shfl_up(inc, o, 64);
        if (lane >= o) inc += x;
    }
    if (lane == 63) wsum[w] = inc;
    __syncthreads();
    int woff = 0;
    for (int i = 0; i < w; ++i) woff += wsum[i];
    ofs[t] = base + woff + inc - d;
    __syncthreads();
    int node = nstart + t;
    if (node < N_NODES) row_ptr[node] = ofs[t];
    if (b == 0 && t == 0) row_ptr[N_NODES] = N_EDGES;
    fc[t] = 0;
    __syncthreads();
    for (int i = base + t; i < bend; i += 256) {
        unsigned p = bbuf[i];
        int dl = (int)(p & 255u);
        int pos = atomicAdd(&fc[dl], 1);
        csr[ofs[dl] + pos] = (int)(p >> 8);
    }
}

// ---------------- feats -> bf16 padded copy [N][80], uint-packed ----------------

__global__ void k_feats_bf(const float* __restrict__ feats, short* __restrict__ fbf) {
    int idx = blockIdx.x * blockDim.x + threadIdx.x;  // uint index
    if (idx >= N_NODES * (FBF_LD / 2)) return;
    int n = idx / (FBF_LD / 2), c2 = idx - n * (FBF_LD / 2);
    int c0 = 2 * c2, c1 = 2 * c2 + 1;
    float v0 = (c0 < F_IN) ? feats[(size_t)n * F_IN + c0] : 0.f;
    float v1 = (c1 < F_IN) ? feats[(size_t)n * F_IN + c1] : 0.f;
    ((unsigned*)fbf)[idx] = bpack(v0, v1);
}

// ---------------- Weight preconvert: Wt[col][k], bf16 hi/lo ----------------

template <int KP, int K1, int AGG0>
__global__ void k_wconv(const float* __restrict__ Ws, const float* __restrict__ Wn,
                        short* __restrict__ Whi, short* __restrict__ Wlo) {
    int idx = blockIdx.x * blockDim.x + threadIdx.x;
    if (idx >= 112 * KP) return;
    int col = idx / KP, k = idx - col * KP;
    float v = 0.f;
    if (col < HID) {
        if (k < K1) v = Ws[k * HID + col];
        else if (k >= AGG0 && k < AGG0 + K1) v = Wn[(k - AGG0) * HID + col];
    }
    unsigned short hi = f2bf(v);
    unsigned short lo = f2bf(v - bf2f(hi));
    Whi[idx] = (short)hi;
    Wlo[idx] = (short)lo;
}

// ---------------- prep1: agt[v] = mean-agg of neighbor feats (bf16, 80 cols) ----------------

__global__ __launch_bounds__(256) void k_prep1(const short* __restrict__ fbf,
                        const int* __restrict__ row_ptr, const int* __restrict__ csr,
                        short* __restrict__ agt) {
    int wid = threadIdx.x >> 6, lane = threadIdx.x & 63;
    int v = blockIdx.x * 4 + wid;
    if (v >= N_NODES) return;
    int h = lane >> 5, q = lane & 31;
    int s = row_ptr[v], e = row_ptr[v + 1];
    float a0 = 0.f, a1 = 0.f, a2 = 0.f, a3 = 0.f;
    if (q < 19) {
        const char* Fb = (const char*)fbf;
        int j = s;
        for (; j + 7 < e; j += 8) {
            uint2 w0 = *(const uint2*)(Fb + (size_t)csr[j + h] * (FBF_LD * 2) + q * 8);
            uint2 w1 = *(const uint2*)(Fb + (size_t)csr[j + 2 + h] * (FBF_LD * 2) + q * 8);
            uint2 w2 = *(const uint2*)(Fb + (size_t)csr[j + 4 + h] * (FBF_LD * 2) + q * 8);
            uint2 w3 = *(const uint2*)(Fb + (size_t)csr[j + 6 + h] * (FBF_LD * 2) + q * 8);
            a0 += blo(w0.x) + blo(w1.x) + blo(w2.x) + blo(w3.x);
            a1 += bhi(w0.x) + bhi(w1.x) + bhi(w2.x) + bhi(w3.x);
            a2 += blo(w0.y) + blo(w1.y) + blo(w2.y) + blo(w3.y);
            a3 += bhi(w0.y) + bhi(w1.y) + bhi(w2.y) + bhi(w3.y);
        }
        for (; j < e; j += 2) {
            int ej = j + h;
            if (ej < e) {
                uint2 w = *(const uint2*)(Fb + (size_t)csr[ej] * (FBF_LD * 2) + q * 8);
                a0 += blo(w.x); a1 += bhi(w.x); a2 += blo(w.y); a3 += bhi(w.y);
            }
        }
    }
    a0 += __shfl_xor(a0, 32, 64);
    a1 += __shfl_xor(a1, 32, 64);
    a2 += __shfl_xor(a2, 32, 64);
    a3 += __shfl_xor(a3, 32, 64);
    float inv = 1.0f / fmaxf((float)(e - s), 1.0f);
    if (h == 0 && q < 20) {  // shorts 4q..4q+3 (zeros for q>=19 since loads were skipped)
        store8((char*)agt + (size_t)v * (AGT_LD * 2) + q * 8,
               bpack(a0 * inv, a1 * inv), bpack(a2 * inv, a3 * inv));
    }
}

// ---------------- prep2: X2[:,100..223] = [mean-agg fp8(h1) | 0] ----------------
// Gathers from fp8 h1c8 [N][128] bytes (cols 0..99 valid). lane q<25 loads uint (4 fp8).

__global__ __launch_bounds__(256) void k_prep2(const unsigned char* __restrict__ h1c8,
                        const int* __restrict__ row_ptr, const int* __restrict__ csr,
                        short* __restrict__ X2) {
    int wid = threadIdx.x >> 6, lane = threadIdx.x & 63;
    int v = blockIdx.x * 4 + wid;
    if (v >= N_NODES) return;
    int h = lane >> 5, q = lane & 31;
    int s = row_ptr[v], e = row_ptr[v + 1];
    float a0 = 0.f, a1 = 0.f, a2 = 0.f, a3 = 0.f;
    if (q < 25) {
        int j = s;
        for (; j + 7 < e; j += 8) {
            unsigned w0 = *(const unsigned*)(h1c8 + (size_t)csr[j + h] * H1C8_LD + q * 4);
            unsigned w1 = *(const unsigned*)(h1c8 + (size_t)csr[j + 2 + h] * H1C8_LD + q * 4);
            unsigned w2 = *(const unsigned*)(h1c8 + (size_t)csr[j + 4 + h] * H1C8_LD + q * 4);
            unsigned w3 = *(const unsigned*)(h1c8 + (size_t)csr[j + 6 + h] * H1C8_LD + q * 4);
            float x0, x1, x2, x3;
            dec_fp8x4(w0, x0, x1, x2, x3); a0 += x0; a1 += x1; a2 += x2; a3 += x3;
            dec_fp8x4(w1, x0, x1, x2, x3); a0 += x0; a1 += x1; a2 += x2; a3 += x3;
            dec_fp8x4(w2, x0, x1, x2, x3); a0 += x0; a1 += x1; a2 += x2; a3 += x3;
            dec_fp8x4(w3, x0, x1, x2, x3); a0 += x0; a1 += x1; a2 += x2; a3 += x3;
        }
        for (; j < e; j += 2) {
            int ej = j + h;
            if (ej < e) {
                unsigned w = *(const unsigned*)(h1c8 + (size_t)csr[ej] * H1C8_LD + q * 4);
                float x0, x1, x2, x3;
                dec_fp8x4(w, x0, x1, x2, x3); a0 += x0; a1 += x1; a2 += x2; a3 += x3;
            }
        }
    }
    a0 += __shfl_xor(a0, 32, 64);
    a1 += __shfl_xor(a1, 32, 64);
    a2 += __shfl_xor(a2, 32, 64);
    a3 += __shfl_xor(a3, 32, 64);
    float inv = 1.0f / fmaxf((float)(e - s), 1.0f);
    char* Xw = (char*)X2 + (size_t)v * (KP2 * 2);           // 448B row
    if (h == 0 && q < 25) {                                  // agg: shorts 100+4q..100+4q+3
        store8(Xw + 200 + q * 8, bpack(a0 * inv, a1 * inv), bpack(a2 * inv, a3 * inv));
    }
    if (h == 1 && q < 6) {                                   // zeros: shorts 200..223
        store8(Xw + 400 + q * 8, 0u, 0u);
    }
}

// ---------------- mfma1: h1 = relu([fbf|agt] @ Wt1^T + b1) -> X2 self (bf16) + h1c8 (fp8) ----------------

__global__ __launch_bounds__(256) void k_mfma1(
    const short* __restrict__ fbf, const short* __restrict__ agt,
    const short* __restrict__ Wthi, const short* __restrict__ Wtlo,
    const float* __restrict__ bias,
    short* __restrict__ X2, unsigned char* __restrict__ h1c8) {
    int t = threadIdx.x;
    int wid = t >> 6, lane = t & 63;
    int quad = lane >> 4, lr = lane & 15;
    int rowbase = blockIdx.x * 128 + wid * 32;

    f32x4 acc[2][7];
    #pragma unroll
    for (int rf = 0; rf < 2; ++rf)
        #pragma unroll
        for (int n = 0; n < 7; ++n) acc[rf][n] = (f32x4){0.f, 0.f, 0.f, 0.f};

    #pragma unroll
    for (int c = 0; c < 5; ++c) {
        short8 ah[2], wh[7], wl[7];
        #pragma unroll
        for (int rf = 0; rf < 2; ++rf) {
            int row = rowbase + rf * 16 + lr;
            const short* p;
            if (c < 2) p = fbf + (size_t)row * FBF_LD + c * 32 + quad * 8;
            else if (c == 2) p = (quad < 2) ? fbf + (size_t)row * FBF_LD + 64 + quad * 8
                                            : agt + (size_t)row * AGT_LD + (quad - 2) * 8;
            else p = agt + (size_t)row * AGT_LD + (c - 3) * 32 + 16 + quad * 8;
            ah[rf] = *(const short8*)p;
        }
        #pragma unroll
        for (int n = 0; n < 7; ++n) {
            size_t off = (size_t)(n * 16 + lr) * KP1 + c * 32 + quad * 8;
            wh[n] = *(const short8*)(Wthi + off);
            wl[n] = *(const short8*)(Wtlo + off);
        }
        #pragma unroll
        for (int rf = 0; rf < 2; ++rf)
            #pragma unroll
            for (int n = 0; n < 7; ++n) {
                acc[rf][n] = __builtin_amdgcn_mfma_f32_16x16x32_bf16(ah[rf], wh[n], acc[rf][n], 0, 0, 0);
                acc[rf][n] = __builtin_amdgcn_mfma_f32_16x16x32_bf16(ah[rf], wl[n], acc[rf][n], 0, 0, 0);
            }
    }

    #pragma unroll
    for (int rf = 0; rf < 2; ++rf) {
        #pragma unroll
        for (int n = 0; n < 7; ++n) {
            int col = n * 16 + lr;
            if (col < HID) {
                float bv = bias[col];
                #pragma unroll
                for (int r = 0; r < 4; ++r) {
                    int row = rowbase + rf * 16 + quad * 4 + r;
                    if (row < N_NODES) {
                        float v = fmaxf(acc[rf][n][r] + bv, 0.f);
                        X2[(size_t)row * KP2 + col] = (short)f2bf(v);
                        h1c8[(size_t)row * H1C8_LD + col] = enc_fp8(v);
                    }
                }
            }
        }
    }
}

// ---------------- mfma2: h2 = relu(X2 @ Wt2^T + b2) -> bf16 [N][100] ----------------

__global__ __launch_bounds__(256) void k_mfma2(
    const short* __restrict__ X2,
    const short* __restrict__ Wthi, const short* __restrict__ Wtlo,
    const float* __restrict__ bias, short* __restrict__ h2c) {
    int t = threadIdx.x;
    int wid = t >> 6, lane = t & 63;
    int quad = lane >> 4, lr = lane & 15;
    int rowbase = blockIdx.x * 128 + wid * 32;

    f32x4 acc[2][7];
    #pragma unroll
    for (int rf = 0; rf < 2; ++rf)
        #pragma unroll
        for (int n = 0; n < 7; ++n) acc[rf][n] = (f32x4){0.f, 0.f, 0.f, 0.f};

    #pragma unroll
    for (int c = 0; c < 7; ++c) {
        short8 ah[2], wh[7], wl[7];
        #pragma unroll
        for (int rf = 0; rf < 2; ++rf) {
            size_t off = (size_t)(rowbase + rf * 16 + lr) * KP2 + c * 32 + quad * 8;
            ah[rf] = *(const short8*)(X2 + off);
        }
        #pragma unroll
        for (int n = 0; n < 7; ++n) {
            size_t off = (size_t)(n * 16 + lr) * KP2 + c * 32 + quad * 8;
            wh[n] = *(const short8*)(Wthi + off);
            wl[n] = *(const short8*)(Wtlo + off);
        }
        #pragma unroll
        for (int rf = 0; rf < 2; ++rf)
            #pragma unroll
            for (int n = 0; n < 7; ++n) {
                acc[rf][n] = __builtin_amdgcn_mfma_f32_16x16x32_bf16(ah[rf], wh[n], acc[rf][n], 0, 0, 0);
                acc[rf][n] = __builtin_amdgcn_mfma_f32_16x16x32_bf16(ah[rf], wl[n], acc[rf][n], 0, 0, 0);
            }
    }

    #pragma unroll
    for (int rf = 0; rf < 2; ++rf) {
        #pragma unroll
        for (int n = 0; n < 7; ++n) {
            int col = n * 16 + lr;
            if (col < HID) {
                float bv = bias[col];
                #pragma unroll
                for (int r = 0; r < 4; ++r) {
                    int row = rowbase + rf * 16 + quad * 4 + r;
                    if (row < N_NODES) {
                        float v = fmaxf(acc[rf][n][r] + bv, 0.f);
                        h2c[(size_t)row * H2_LD + col] = (short)f2bf(v);
                    }
                }
            }
        }
    }
}

// ---------------- Collapsed predictor head: w_eff[200], b_eff ----------------

__global__ void k_weff(const float* __restrict__ Wp1, const float* __restrict__ bp1,
                       const float* __restrict__ Wp2, const float* __restrict__ bp2,
                       float* __restrict__ weff) {
    int t = threadIdx.x;
    if (t < 200) {
        float s = 0.f;
        for (int k = 0; k < 64; ++k) s += Wp1[t * 64 + k] * Wp2[k];
        weff[t] = s;
    } else if (t == 200) {
        float s = bp2[0];
        for (int k = 0; k < 64; ++k) s += bp1[k] * Wp2[k];
        weff[200] = s;
    }
}

// ---------------- Readout (bf16 h2, uint loads): per-graph weighted sum + max, fused head ----------------

__global__ __launch_bounds__(128) void k_readout(
    const unsigned short* __restrict__ h2c, const int* __restrict__ graph_ids,
    const float* __restrict__ w_atom, const float* __restrict__ b_atom,
    const float* __restrict__ weff, float* __restrict__ out) {
    int g = blockIdx.x;
    int t = threadIdx.x, lane = t & 63, w = t >> 6;

    int s_, e_;
    {
        int l = 0, r = N_NODES;
        while (l < r) { int m = (l + r) >> 1; if (graph_ids[m] < g) l = m + 1; else r = m; }
        s_ = l;
        l = s_; r = N_NODES;
        while (l < r) { int m = (l + r) >> 1; if (graph_ids[m] < g + 1) l = m + 1; else r = m; }
        e_ = l;
    }

    float ba = b_atom[0];
    // lane l < 50 owns cols 2l, 2l+1
    float wa0 = 0.f, wa1 = 0.f;
    if (lane < 50) {
        float2 wv = *(const float2*)&w_atom[2 * lane];
        wa0 = wv.x; wa1 = wv.y;
    }
    float sum0 = 0.f, sum1 = 0.f, mx0 = 0.f, mx1 = 0.f;  // h >= 0 (relu)
    for (int i = s_ + w; i < e_; i += 2) {
        float v0 = 0.f, v1 = 0.f;
        if (lane < 50) {
            unsigned wv = *(const unsigned*)(h2c + (size_t)i * H2_LD + 2 * lane);
            v0 = blo(wv); v1 = bhi(wv);
        }
        float p = v0 * wa0 + v1 * wa1;
        #pragma unroll
        for (int off = 32; off; off >>= 1) p += __shfl_xor(p, off, 64);
        float wt = 1.f / (1.f + __expf(-(p + ba)));
        sum0 += v0 * wt;
        sum1 += v1 * wt;
        mx0 = fmaxf(mx0, v0);
        mx1 = fmaxf(mx1, v1);
    }

    __shared__ float ssum[2][HID];
    __shared__ float smx[2][HID];
    if (lane < 50) {
        ssum[w][2 * lane] = sum0;
        ssum[w][2 * lane + 1] = sum1;
        smx[w][2 * lane] = mx0;
        smx[w][2 * lane + 1] = mx1;
    }
    __syncthreads();

    float contrib = 0.f;
    if (t < HID) {
        float sumf = ssum[0][t] + ssum[1][t];
        float mxf = fmaxf(smx[0][t], smx[1][t]);
        contrib = sumf * weff[t] + mxf * weff[HID + t];
    }
    #pragma unroll
    for (int off = 32; off; off >>= 1) contrib += __shfl_xor(contrib, off, 64);
    __shared__ float red[2];
    if (lane == 0) red[w] = contrib;
    __syncthreads();
    if (t == 0) out[g] = red[0] + red[1] + weff[200];
}

// ---------------- launch ----------------

extern "C" void kernel_launch(void* const* d_in, const int* in_sizes, int n_in,
                              void* d_out, int out_size, void* d_ws, size_t ws_size,
                              hipStream_t stream) {
    const float* node_feats = (const float*)d_in[0];
    const int* src = (const int*)d_in[1];
    const int* dst = (const int*)d_in[2];
    const int* gid = (const int*)d_in[3];
    const float* Ws1 = (const float*)d_in[5];
    const float* Wn1 = (const float*)d_in[6];
    const float* b1 = (const float*)d_in[7];
    const float* Ws2 = (const float*)d_in[8];
    const float* Wn2 = (const float*)d_in[9];
    const float* b2 = (const float*)d_in[10];
    const float* w_atom = (const float*)d_in[11];
    const float* b_atom = (const float*)d_in[12];
    const float* Wp1 = (const float*)d_in[13];
    const float* bp1 = (const float*)d_in[14];
    const float* Wp2 = (const float*)d_in[15];
    const float* bp2 = (const float*)d_in[16];
    float* out = (float*)d_out;

    char* ws = (char*)d_ws;
    size_t off = 0;
    auto alloc = [&](size_t bytes) -> void* {
        void* p = (void*)(ws + off);
        off += (bytes + 255) & ~(size_t)255;
        return p;
    };
    int* row_ptr = (int*)alloc((N_NODES + 1) * sizeof(int));
    int* bucket_cnt = (int*)alloc(NB * sizeof(int));
    int* bucket_base = (int*)alloc((NB + 1) * sizeof(int));
    int* bucket_fill = (int*)alloc(NB * sizeof(int));
    int* csr = (int*)alloc((size_t)N_EDGES * sizeof(int));
    unsigned* bbuf = (unsigned*)alloc((size_t)N_EDGES * sizeof(unsigned));    // 6.4 MB
    short* fbf = (short*)alloc((size_t)N_PAD * FBF_LD * sizeof(short));       // 16 MB
    short* agt = (short*)alloc((size_t)N_PAD * AGT_LD * sizeof(short));       // 16 MB
    short* X2 = (short*)alloc((size_t)N_PAD * KP2 * sizeof(short));           // 44.8 MB
    unsigned char* h1c8 = (unsigned char*)alloc((size_t)N_NODES * H1C8_LD);   // 12.8 MB
    short* h2c = (short*)alloc((size_t)N_NODES * H2_LD * sizeof(short));      // 20 MB
    short* Wt1hi = (short*)alloc(112 * KP1 * sizeof(short));
    short* Wt1lo = (short*)alloc(112 * KP1 * sizeof(short));
    short* Wt2hi = (short*)alloc(112 * KP2 * sizeof(short));
    short* Wt2lo = (short*)alloc(112 * KP2 * sizeof(short));
    float* weff = (float*)alloc(256 * sizeof(float));

    hipMemsetAsync(bucket_cnt, 0, NB * sizeof(int), stream);
    hipMemsetAsync(bucket_fill, 0, NB * sizeof(int), stream);

    k_bcnt<<<NBB, 256, 0, stream>>>(dst, bucket_cnt);
    k_bscan<<<1, 512, 0, stream>>>(bucket_cnt, bucket_base);
    k_bin<<<NBB, 256, 0, stream>>>(src, dst, bucket_base, bucket_fill, bbuf);
    k_scatter<<<NB, 256, 0, stream>>>(bbuf, bucket_base, row_ptr, csr);

    k_feats_bf<<<(N_NODES * (FBF_LD / 2) + 255) / 256, 256, 0, stream>>>(node_feats, fbf);
    k_wconv<KP1, F_IN, 80><<<(112 * KP1 + 255) / 256, 256, 0, stream>>>(Ws1, Wn1, Wt1hi, Wt1lo);
    k_wconv<KP2, HID, 100><<<(112 * KP2 + 255) / 256, 256, 0, stream>>>(Ws2, Wn2, Wt2hi, Wt2lo);

    k_prep1<<<(N_NODES + 3) / 4, 256, 0, stream>>>(fbf, row_ptr, csr, agt);
    k_mfma1<<<N_PAD / 128, 256, 0, stream>>>(fbf, agt, Wt1hi, Wt1lo, b1, X2, h1c8);
    k_prep2<<<(N_NODES + 3) / 4, 256, 0, stream>>>(h1c8, row_ptr, csr, X2);
    k_mfma2<<<N_PAD / 128, 256, 0, stream>>>(X2, Wt2hi, Wt2lo, b2, h2c);

    k_weff<<<1, 256, 0, stream>>>(Wp1, bp1, Wp2, bp2, weff);
    k_readout<<<N_GRAPHS, 128, 0, stream>>>((const unsigned short*)h2c, gid, w_atom, b_atom, weff, out);
}

// Round 11
// 290.083 us; speedup vs baseline: 1.5206x; 1.0947x over previous
//
#include <hip/hip_runtime.h>

#define N_NODES 100000
#define N_PAD   100096   // 782 blocks * 128 rows
#define N_EDGES 1600000
#define N_GRAPHS 1024
#define F_IN 74
#define HID 100

#define KP1 160   // W1 layout: [self 0..73 | 0 | agg 80..153 | 0]; A from fbf(k<80)+agt(k>=80)
#define KP2 224   // [self h1 0..99 | agg 100..199 | 0 200..223]

#define FBF_LD 80    // bf16 feats rows (160B)
#define F8T_LD 80    // fp8 feats rows (80B stride -> always 2 cache lines)
#define AGT_LD 80    // bf16 agg1 rows (160B)
#define H1C8_LD 128  // fp8 h1 compact rows (128B)
#define H2_LD  100   // bf16 h2 rows (200B)

#define NB ((N_NODES + 255) / 256)   // 391 dst-buckets of 256 nodes
#define BKCAP 8192                   // bbuf/csr slots per bucket (avg ~4092, 2x headroom)
#define BIN_EPB 4096                 // edges per binning block
#define NBB ((N_EDGES + BIN_EPB - 1) / BIN_EPB)

typedef __attribute__((ext_vector_type(8))) short short8;
typedef __attribute__((ext_vector_type(4))) float f32x4;
typedef __attribute__((ext_vector_type(2))) float f32x2;

#if defined(__has_builtin)
#if __has_builtin(__builtin_amdgcn_cvt_pk_f32_fp8) && __has_builtin(__builtin_amdgcn_cvt_pk_fp8_f32)
#define HAVE_FP8 1
#endif
#endif

__device__ __forceinline__ unsigned short f2bf(float x) {
    union { float f; unsigned u; } c; c.f = x;
    unsigned u = c.u;
    unsigned r = (u + 0x7fffu + ((u >> 16) & 1u)) >> 16;
    return (unsigned short)r;
}
__device__ __forceinline__ float bf2f(unsigned short h) {
    union { unsigned u; float f; } c; c.u = ((unsigned)h) << 16;
    return c.f;
}
__device__ __forceinline__ float blo(unsigned w) { return bf2f((unsigned short)(w & 0xffffu)); }
__device__ __forceinline__ float bhi(unsigned w) { return bf2f((unsigned short)(w >> 16)); }
__device__ __forceinline__ unsigned bpack(float a, float b) {
    return (unsigned)f2bf(a) | ((unsigned)f2bf(b) << 16);
}
__device__ __forceinline__ void store8(void* p, unsigned lo, unsigned hi) {
    unsigned long long v = (unsigned long long)lo | ((unsigned long long)hi << 32);
    *(unsigned long long*)p = v;
}

// ---- fp8 e4m3 helpers (sign-aware) ----
__device__ __forceinline__ unsigned char enc_fp8_1(float v) {
#ifdef HAVE_FP8
    return (unsigned char)__builtin_amdgcn_cvt_pk_fp8_f32(v, 0.f, 0, false);
#else
    unsigned sgn = v < 0.f ? 0x80u : 0u;
    float m = fabsf(v);
    unsigned char mag;
    if (m < 0.015625f) {
        int q = (int)(m * 512.0f + 0.5f);
        mag = (unsigned char)(q > 7 ? 7 : q);
    } else {
        union { float f; unsigned u; } c; c.f = m;
        unsigned r = c.u + 0x7ffff + ((c.u >> 20) & 1u);
        int e = (int)(r >> 23) - 127;
        mag = (e > 8) ? (unsigned char)0x7e : (unsigned char)(((e + 7) << 3) | ((r >> 20) & 7u));
    }
    return (unsigned char)(sgn | mag);
#endif
}
__device__ __forceinline__ unsigned enc_fp8x4(float v0, float v1, float v2, float v3) {
#ifdef HAVE_FP8
    int r = __builtin_amdgcn_cvt_pk_fp8_f32(v0, v1, 0, false);
    r = __builtin_amdgcn_cvt_pk_fp8_f32(v2, v3, r, true);
    return (unsigned)r;
#else
    return (unsigned)enc_fp8_1(v0) | ((unsigned)enc_fp8_1(v1) << 8) |
           ((unsigned)enc_fp8_1(v2) << 16) | ((unsigned)enc_fp8_1(v3) << 24);
#endif
}
__device__ __forceinline__ void dec_fp8x4(unsigned w, float& x0, float& x1, float& x2, float& x3) {
#ifdef HAVE_FP8
    f32x2 lo = __builtin_amdgcn_cvt_pk_f32_fp8((int)w, false);
    f32x2 hi = __builtin_amdgcn_cvt_pk_f32_fp8((int)w, true);
    x0 = lo.x; x1 = lo.y; x2 = hi.x; x3 = hi.y;
#else
    auto d1 = [](unsigned b) -> float {
        float s = (b & 0x80u) ? -1.f : 1.f;
        b &= 0x7fu;
        if (b < 8) return s * (float)b * 0.001953125f;
        union { unsigned u; float f; } c;
        c.u = ((((b >> 3) & 15u) - 7 + 127) << 23) | ((b & 7u) << 20);
        return s * c.f;
    };
    x0 = d1(w & 0xffu); x1 = d1((w >> 8) & 0xffu);
    x2 = d1((w >> 16) & 0xffu); x3 = d1(w >> 24);
#endif
}

// ---------------- binned CSR fill (fixed-capacity buckets) ----------------
// bucket b = dst>>8; packed entry = (src<<8) | (dst&255); region [b*BKCAP, b*BKCAP+fill).

__global__ __launch_bounds__(256) void k_bin(const int* __restrict__ src,
                                             const int* __restrict__ dst,
                                             int* __restrict__ bucket_fill,
                                             unsigned* __restrict__ bbuf) {
    __shared__ int cnt[NB];
    __shared__ int base[NB];
    int t = threadIdx.x;
    for (int i = t; i < NB; i += 256) cnt[i] = 0;
    __syncthreads();
    int e0 = blockIdx.x * BIN_EPB;
    int e1 = e0 + BIN_EPB < N_EDGES ? e0 + BIN_EPB : N_EDGES;
    for (int e = e0 + t; e < e1; e += 256) {
        atomicAdd(&cnt[dst[e] >> 8], 1);
    }
    __syncthreads();
    for (int i = t; i < NB; i += 256) {
        int c = cnt[i];
        base[i] = c ? atomicAdd(&bucket_fill[i], c) : 0;
        cnt[i] = 0;
    }
    __syncthreads();
    for (int e = e0 + t; e < e1; e += 256) {
        int d = dst[e];
        int b = d >> 8;
        int pos = atomicAdd(&cnt[b], 1);
        bbuf[(size_t)b * BKCAP + base[b] + pos] = ((unsigned)src[e] << 8) | (unsigned)(d & 255);
    }
}

// scatter: builds rp2 (per-node start,end) from its bucket run, then places csr entries.

__global__ __launch_bounds__(256) void k_scatter(const unsigned* __restrict__ bbuf,
                                                 const int* __restrict__ bucket_fill,
                                                 int2* __restrict__ rp2,
                                                 int* __restrict__ csr) {
    __shared__ int fc[256];
    __shared__ int ofs[256];
    __shared__ int wsum[4];
    int b = blockIdx.x, t = threadIdx.x;
    int nstart = b << 8;
    int base = b * BKCAP;
    int bend = base + bucket_fill[b];
    fc[t] = 0;
    __syncthreads();
    for (int i = base + t; i < bend; i += 256)
        atomicAdd(&fc[bbuf[i] & 255u], 1);
    __syncthreads();
    int d = fc[t];
    int lane = t & 63, w = t >> 6;
    int inc = d;
    #pragma unroll
    for (int o = 1; o < 64; o <<= 1) {
        int x = __shfl_up(inc, o, 64);
        if (lane >= o) inc += x;
    }
    if (lane == 63) wsum[w] = inc;
    __syncthreads();
    int woff = 0;
    for (int i = 0; i < w; ++i) woff += wsum[i];
    ofs[t] = base + woff + inc - d;
    __syncthreads();
    int node = nstart + t;
    if (node < N_NODES) rp2[node] = make_int2(ofs[t], ofs[t] + d);
    fc[t] = 0;
    __syncthreads();
    for (int i = base + t; i < bend; i += 256) {
        unsigned p = bbuf[i];
        int dl = (int)(p & 255u);
        int pos = atomicAdd(&fc[dl], 1);
        csr[ofs[dl] + pos] = (int)(p >> 8);
    }
}

// ---------------- feats -> bf16 copy [N][80] + fp8 copy [N][80B] ----------------

__global__ void k_feats(const float* __restrict__ feats, short* __restrict__ fbf,
                        unsigned* __restrict__ f8t) {
    int idx = blockIdx.x * blockDim.x + threadIdx.x;  // 4-col group index
    if (idx >= N_NODES * (F8T_LD / 4)) return;
    int n = idx / (F8T_LD / 4), g = idx - n * (F8T_LD / 4);
    int c0 = 4 * g;
    const float* r = feats + (size_t)n * F_IN;
    float v0 = (c0 + 0 < F_IN) ? r[c0 + 0] : 0.f;
    float v1 = (c0 + 1 < F_IN) ? r[c0 + 1] : 0.f;
    float v2 = (c0 + 2 < F_IN) ? r[c0 + 2] : 0.f;
    float v3 = (c0 + 3 < F_IN) ? r[c0 + 3] : 0.f;
    unsigned* fb = (unsigned*)fbf + (size_t)n * (FBF_LD / 2) + 2 * g;
    fb[0] = bpack(v0, v1);
    fb[1] = bpack(v2, v3);
    f8t[idx] = enc_fp8x4(v0, v1, v2, v3);
}

// ---------------- Weight preconvert: Wt[col][k], bf16 hi/lo ----------------

template <int KP, int K1, int AGG0>
__global__ void k_wconv(const float* __restrict__ Ws, const float* __restrict__ Wn,
                        short* __restrict__ Whi, short* __restrict__ Wlo) {
    int idx = blockIdx.x * blockDim.x + threadIdx.x;
    if (idx >= 112 * KP) return;
    int col = idx / KP, k = idx - col * KP;
    float v = 0.f;
    if (col < HID) {
        if (k < K1) v = Ws[k * HID + col];
        else if (k >= AGG0 && k < AGG0 + K1) v = Wn[(k - AGG0) * HID + col];
    }
    unsigned short hi = f2bf(v);
    unsigned short lo = f2bf(v - bf2f(hi));
    Whi[idx] = (short)hi;
    Wlo[idx] = (short)lo;
}

// ---------------- prep1: agt[v] = mean-agg of fp8 neighbor feats (bf16 out, 80 cols) ----------------
// lane q<19 loads uint (4 fp8 cols) per edge; 80B rows -> exactly 2 lines/edge.

__global__ __launch_bounds__(256) void k_prep1(const unsigned char* __restrict__ f8t,
                        const int2* __restrict__ rp2, const int* __restrict__ csr,
                        short* __restrict__ agt) {
    int wid = threadIdx.x >> 6, lane = threadIdx.x & 63;
    int v = blockIdx.x * 4 + wid;
    if (v >= N_NODES) return;
    int h = lane >> 5, q = lane & 31;
    int2 se = rp2[v];
    int s = se.x, e = se.y;
    float a0 = 0.f, a1 = 0.f, a2 = 0.f, a3 = 0.f;
    if (q < 19) {
        int j = s;
        for (; j + 7 < e; j += 8) {
            unsigned w0 = *(const unsigned*)(f8t + (size_t)csr[j + h] * F8T_LD + q * 4);
            unsigned w1 = *(const unsigned*)(f8t + (size_t)csr[j + 2 + h] * F8T_LD + q * 4);
            unsigned w2 = *(const unsigned*)(f8t + (size_t)csr[j + 4 + h] * F8T_LD + q * 4);
            unsigned w3 = *(const unsigned*)(f8t + (size_t)csr[j + 6 + h] * F8T_LD + q * 4);
            float x0, x1, x2, x3;
            dec_fp8x4(w0, x0, x1, x2, x3); a0 += x0; a1 += x1; a2 += x2; a3 += x3;
            dec_fp8x4(w1, x0, x1, x2, x3); a0 += x0; a1 += x1; a2 += x2; a3 += x3;
            dec_fp8x4(w2, x0, x1, x2, x3); a0 += x0; a1 += x1; a2 += x2; a3 += x3;
            dec_fp8x4(w3, x0, x1, x2, x3); a0 += x0; a1 += x1; a2 += x2; a3 += x3;
        }
        for (; j < e; j += 2) {
            int ej = j + h;
            if (ej < e) {
                unsigned w = *(const unsigned*)(f8t + (size_t)csr[ej] * F8T_LD + q * 4);
                float x0, x1, x2, x3;
                dec_fp8x4(w, x0, x1, x2, x3); a0 += x0; a1 += x1; a2 += x2; a3 += x3;
            }
        }
    }
    a0 += __shfl_xor(a0, 32, 64);
    a1 += __shfl_xor(a1, 32, 64);
    a2 += __shfl_xor(a2, 32, 64);
    a3 += __shfl_xor(a3, 32, 64);
    float inv = 1.0f / fmaxf((float)(e - s), 1.0f);
    if (h == 0 && q < 20) {  // shorts 4q..4q+3 (q=19 -> zeros)
        store8((char*)agt + (size_t)v * (AGT_LD * 2) + q * 8,
               bpack(a0 * inv, a1 * inv), bpack(a2 * inv, a3 * inv));
    }
}

// ---------------- prep2: X2[:,100..223] = [mean-agg fp8(h1) | 0] ----------------

__global__ __launch_bounds__(256) void k_prep2(const unsigned char* __restrict__ h1c8,
                        const int2* __restrict__ rp2, const int* __restrict__ csr,
                        short* __restrict__ X2) {
    int wid = threadIdx.x >> 6, lane = threadIdx.x & 63;
    int v = blockIdx.x * 4 + wid;
    if (v >= N_NODES) return;
    int h = lane >> 5, q = lane & 31;
    int2 se = rp2[v];
    int s = se.x, e = se.y;
    float a0 = 0.f, a1 = 0.f, a2 = 0.f, a3 = 0.f;
    if (q < 25) {
        int j = s;
        for (; j + 7 < e; j += 8) {
            unsigned w0 = *(const unsigned*)(h1c8 + (size_t)csr[j + h] * H1C8_LD + q * 4);
            unsigned w1 = *(const unsigned*)(h1c8 + (size_t)csr[j + 2 + h] * H1C8_LD + q * 4);
            unsigned w2 = *(const unsigned*)(h1c8 + (size_t)csr[j + 4 + h] * H1C8_LD + q * 4);
            unsigned w3 = *(const unsigned*)(h1c8 + (size_t)csr[j + 6 + h] * H1C8_LD + q * 4);
            float x0, x1, x2, x3;
            dec_fp8x4(w0, x0, x1, x2, x3); a0 += x0; a1 += x1; a2 += x2; a3 += x3;
            dec_fp8x4(w1, x0, x1, x2, x3); a0 += x0; a1 += x1; a2 += x2; a3 += x3;
            dec_fp8x4(w2, x0, x1, x2, x3); a0 += x0; a1 += x1; a2 += x2; a3 += x3;
            dec_fp8x4(w3, x0, x1, x2, x3); a0 += x0; a1 += x1; a2 += x2; a3 += x3;
        }
        for (; j < e; j += 2) {
            int ej = j + h;
            if (ej < e) {
                unsigned w = *(const unsigned*)(h1c8 + (size_t)csr[ej] * H1C8_LD + q * 4);
                float x0, x1, x2, x3;
                dec_fp8x4(w, x0, x1, x2, x3); a0 += x0; a1 += x1; a2 += x2; a3 += x3;
            }
        }
    }
    a0 += __shfl_xor(a0, 32, 64);
    a1 += __shfl_xor(a1, 32, 64);
    a2 += __shfl_xor(a2, 32, 64);
    a3 += __shfl_xor(a3, 32, 64);
    float inv = 1.0f / fmaxf((float)(e - s), 1.0f);
    char* Xw = (char*)X2 + (size_t)v * (KP2 * 2);           // 448B row
    if (h == 0 && q < 25) {                                  // agg: shorts 100+4q..100+4q+3
        store8(Xw + 200 + q * 8, bpack(a0 * inv, a1 * inv), bpack(a2 * inv, a3 * inv));
    }
    if (h == 1 && q < 6) {                                   // zeros: shorts 200..223
        store8(Xw + 400 + q * 8, 0u, 0u);
    }
}

// ---------------- mfma1: h1 = relu([fbf|agt] @ Wt1^T + b1) -> X2 self (bf16) + h1c8 (fp8) ----------------

__global__ __launch_bounds__(256) void k_mfma1(
    const short* __restrict__ fbf, const short* __restrict__ agt,
    const short* __restrict__ Wthi, const short* __restrict__ Wtlo,
    const float* __restrict__ bias,
    short* __restrict__ X2, unsigned char* __restrict__ h1c8) {
    int t = threadIdx.x;
    int wid = t >> 6, lane = t & 63;
    int quad = lane >> 4, lr = lane & 15;
    int rowbase = blockIdx.x * 128 + wid * 32;

    f32x4 acc[2][7];
    #pragma unroll
    for (int rf = 0; rf < 2; ++rf)
        #pragma unroll
        for (int n = 0; n < 7; ++n) acc[rf][n] = (f32x4){0.f, 0.f, 0.f, 0.f};

    #pragma unroll
    for (int c = 0; c < 5; ++c) {
        short8 ah[2], wh[7], wl[7];
        #pragma unroll
        for (int rf = 0; rf < 2; ++rf) {
            int row = rowbase + rf * 16 + lr;
            const short* p;
            if (c < 2) p = fbf + (size_t)row * FBF_LD + c * 32 + quad * 8;
            else if (c == 2) p = (quad < 2) ? fbf + (size_t)row * FBF_LD + 64 + quad * 8
                                            : agt + (size_t)row * AGT_LD + (quad - 2) * 8;
            else p = agt + (size_t)row * AGT_LD + (c - 3) * 32 + 16 + quad * 8;
            ah[rf] = *(const short8*)p;
        }
        #pragma unroll
        for (int n = 0; n < 7; ++n) {
            size_t off = (size_t)(n * 16 + lr) * KP1 + c * 32 + quad * 8;
            wh[n] = *(const short8*)(Wthi + off);
            wl[n] = *(const short8*)(Wtlo + off);
        }
        #pragma unroll
        for (int rf = 0; rf < 2; ++rf)
            #pragma unroll
            for (int n = 0; n < 7; ++n) {
                acc[rf][n] = __builtin_amdgcn_mfma_f32_16x16x32_bf16(ah[rf], wh[n], acc[rf][n], 0, 0, 0);
                acc[rf][n] = __builtin_amdgcn_mfma_f32_16x16x32_bf16(ah[rf], wl[n], acc[rf][n], 0, 0, 0);
            }
    }

    #pragma unroll
    for (int rf = 0; rf < 2; ++rf) {
        #pragma unroll
        for (int n = 0; n < 7; ++n) {
            int col = n * 16 + lr;
            if (col < HID) {
                float bv = bias[col];
                #pragma unroll
                for (int r = 0; r < 4; ++r) {
                    int row = rowbase + rf * 16 + quad * 4 + r;
                    if (row < N_NODES) {
                        float v = fmaxf(acc[rf][n][r] + bv, 0.f);
                        X2[(size_t)row * KP2 + col] = (short)f2bf(v);
                        h1c8[(size_t)row * H1C8_LD + col] = enc_fp8_1(v);
                    }
                }
            }
        }
    }
}

// ---------------- mfma2: h2 = relu(X2 @ Wt2^T + b2) -> bf16 [N][100] ----------------

__global__ __launch_bounds__(256) void k_mfma2(
    const short* __restrict__ X2,
    const short* __restrict__ Wthi, const short* __restrict__ Wtlo,
    const float* __restrict__ bias, short* __restrict__ h2c) {
    int t = threadIdx.x;
    int wid = t >> 6, lane = t & 63;
    int quad = lane >> 4, lr = lane & 15;
    int rowbase = blockIdx.x * 128 + wid * 32;

    f32x4 acc[2][7];
    #pragma unroll
    for (int rf = 0; rf < 2; ++rf)
        #pragma unroll
        for (int n = 0; n < 7; ++n) acc[rf][n] = (f32x4){0.f, 0.f, 0.f, 0.f};

    #pragma unroll
    for (int c = 0; c < 7; ++c) {
        short8 ah[2], wh[7], wl[7];
        #pragma unroll
        for (int rf = 0; rf < 2; ++rf) {
            size_t off = (size_t)(rowbase + rf * 16 + lr) * KP2 + c * 32 + quad * 8;
            ah[rf] = *(const short8*)(X2 + off);
        }
        #pragma unroll
        for (int n = 0; n < 7; ++n) {
            size_t off = (size_t)(n * 16 + lr) * KP2 + c * 32 + quad * 8;
            wh[n] = *(const short8*)(Wthi + off);
            wl[n] = *(const short8*)(Wtlo + off);
        }
        #pragma unroll
        for (int rf = 0; rf < 2; ++rf)
            #pragma unroll
            for (int n = 0; n < 7; ++n) {
                acc[rf][n] = __builtin_amdgcn_mfma_f32_16x16x32_bf16(ah[rf], wh[n], acc[rf][n], 0, 0, 0);
                acc[rf][n] = __builtin_amdgcn_mfma_f32_16x16x32_bf16(ah[rf], wl[n], acc[rf][n], 0, 0, 0);
            }
    }

    #pragma unroll
    for (int rf = 0; rf < 2; ++rf) {
        #pragma unroll
        for (int n = 0; n < 7; ++n) {
            int col = n * 16 + lr;
            if (col < HID) {
                float bv = bias[col];
                #pragma unroll
                for (int r = 0; r < 4; ++r) {
                    int row = rowbase + rf * 16 + quad * 4 + r;
                    if (row < N_NODES) {
                        float v = fmaxf(acc[rf][n][r] + bv, 0.f);
                        h2c[(size_t)row * H2_LD + col] = (short)f2bf(v);
                    }
                }
            }
        }
    }
}

// ---------------- Collapsed predictor head: w_eff[200], b_eff ----------------

__global__ void k_weff(const float* __restrict__ Wp1, const float* __restrict__ bp1,
                       const float* __restrict__ Wp2, const float* __restrict__ bp2,
                       float* __restrict__ weff) {
    int t = threadIdx.x;
    if (t < 200) {
        float s = 0.f;
        for (int k = 0; k < 64; ++k) s += Wp1[t * 64 + k] * Wp2[k];
        weff[t] = s;
    } else if (t == 200) {
        float s = bp2[0];
        for (int k = 0; k < 64; ++k) s += bp1[k] * Wp2[k];
        weff[200] = s;
    }
}

// ---------------- Readout (bf16 h2, uint loads): per-graph weighted sum + max, fused head ----------------

__global__ __launch_bounds__(128) void k_readout(
    const unsigned short* __restrict__ h2c, const int* __restrict__ graph_ids,
    const float* __restrict__ w_atom, const float* __restrict__ b_atom,
    const float* __restrict__ weff, float* __restrict__ out) {
    int g = blockIdx.x;
    int t = threadIdx.x, lane = t & 63, w = t >> 6;

    int s_, e_;
    {
        int l = 0, r = N_NODES;
        while (l < r) { int m = (l + r) >> 1; if (graph_ids[m] < g) l = m + 1; else r = m; }
        s_ = l;
        l = s_; r = N_NODES;
        while (l < r) { int m = (l + r) >> 1; if (graph_ids[m] < g + 1) l = m + 1; else r = m; }
        e_ = l;
    }

    float ba = b_atom[0];
    float wa0 = 0.f, wa1 = 0.f;
    if (lane < 50) {
        float2 wv = *(const float2*)&w_atom[2 * lane];
        wa0 = wv.x; wa1 = wv.y;
    }
    float sum0 = 0.f, sum1 = 0.f, mx0 = 0.f, mx1 = 0.f;  // h >= 0 (relu)
    for (int i = s_ + w; i < e_; i += 2) {
        float v0 = 0.f, v1 = 0.f;
        if (lane < 50) {
            unsigned wv = *(const unsigned*)(h2c + (size_t)i * H2_LD + 2 * lane);
            v0 = blo(wv); v1 = bhi(wv);
        }
        float p = v0 * wa0 + v1 * wa1;
        #pragma unroll
        for (int off = 32; off; off >>= 1) p += __shfl_xor(p, off, 64);
        float wt = 1.f / (1.f + __expf(-(p + ba)));
        sum0 += v0 * wt;
        sum1 += v1 * wt;
        mx0 = fmaxf(mx0, v0);
        mx1 = fmaxf(mx1, v1);
    }

    __shared__ float ssum[2][HID];
    __shared__ float smx[2][HID];
    if (lane < 50) {
        ssum[w][2 * lane] = sum0;
        ssum[w][2 * lane + 1] = sum1;
        smx[w][2 * lane] = mx0;
        smx[w][2 * lane + 1] = mx1;
    }
    __syncthreads();

    float contrib = 0.f;
    if (t < HID) {
        float sumf = ssum[0][t] + ssum[1][t];
        float mxf = fmaxf(smx[0][t], smx[1][t]);
        contrib = sumf * weff[t] + mxf * weff[HID + t];
    }
    #pragma unroll
    for (int off = 32; off; off >>= 1) contrib += __shfl_xor(contrib, off, 64);
    __shared__ float red[2];
    if (lane == 0) red[w] = contrib;
    __syncthreads();
    if (t == 0) out[g] = red[0] + red[1] + weff[200];
}

// ---------------- launch ----------------

extern "C" void kernel_launch(void* const* d_in, const int* in_sizes, int n_in,
                              void* d_out, int out_size, void* d_ws, size_t ws_size,
                              hipStream_t stream) {
    const float* node_feats = (const float*)d_in[0];
    const int* src = (const int*)d_in[1];
    const int* dst = (const int*)d_in[2];
    const int* gid = (const int*)d_in[3];
    const float* Ws1 = (const float*)d_in[5];
    const float* Wn1 = (const float*)d_in[6];
    const float* b1 = (const float*)d_in[7];
    const float* Ws2 = (const float*)d_in[8];
    const float* Wn2 = (const float*)d_in[9];
    const float* b2 = (const float*)d_in[10];
    const float* w_atom = (const float*)d_in[11];
    const float* b_atom = (const float*)d_in[12];
    const float* Wp1 = (const float*)d_in[13];
    const float* bp1 = (const float*)d_in[14];
    const float* Wp2 = (const float*)d_in[15];
    const float* bp2 = (const float*)d_in[16];
    float* out = (float*)d_out;

    char* ws = (char*)d_ws;
    size_t off = 0;
    auto alloc = [&](size_t bytes) -> void* {
        void* p = (void*)(ws + off);
        off += (bytes + 255) & ~(size_t)255;
        return p;
    };
    int2* rp2 = (int2*)alloc((size_t)N_NODES * sizeof(int2));
    int* bucket_fill = (int*)alloc(NB * sizeof(int));
    int* csr = (int*)alloc((size_t)NB * BKCAP * sizeof(int));                 // 12.8 MB
    unsigned* bbuf = (unsigned*)alloc((size_t)NB * BKCAP * sizeof(unsigned)); // 12.8 MB
    short* fbf = (short*)alloc((size_t)N_PAD * FBF_LD * sizeof(short));       // 16 MB
    unsigned char* f8t = (unsigned char*)alloc((size_t)N_PAD * F8T_LD);       // 8 MB
    short* agt = (short*)alloc((size_t)N_PAD * AGT_LD * sizeof(short));       // 16 MB
    short* X2 = (short*)alloc((size_t)N_PAD * KP2 * sizeof(short));           // 44.8 MB
    unsigned char* h1c8 = (unsigned char*)alloc((size_t)N_NODES * H1C8_LD);   // 12.8 MB
    short* h2c = (short*)alloc((size_t)N_NODES * H2_LD * sizeof(short));      // 20 MB
    short* Wt1hi = (short*)alloc(112 * KP1 * sizeof(short));
    short* Wt1lo = (short*)alloc(112 * KP1 * sizeof(short));
    short* Wt2hi = (short*)alloc(112 * KP2 * sizeof(short));
    short* Wt2lo = (short*)alloc(112 * KP2 * sizeof(short));
    float* weff = (float*)alloc(256 * sizeof(float));

    hipMemsetAsync(bucket_fill, 0, NB * sizeof(int), stream);

    k_bin<<<NBB, 256, 0, stream>>>(src, dst, bucket_fill, bbuf);
    k_scatter<<<NB, 256, 0, stream>>>(bbuf, bucket_fill, rp2, csr);

    k_feats<<<(N_NODES * (F8T_LD / 4) + 255) / 256, 256, 0, stream>>>(node_feats, fbf, (unsigned*)f8t);
    k_wconv<KP1, F_IN, 80><<<(112 * KP1 + 255) / 256, 256, 0, stream>>>(Ws1, Wn1, Wt1hi, Wt1lo);
    k_wconv<KP2, HID, 100><<<(112 * KP2 + 255) / 256, 256, 0, stream>>>(Ws2, Wn2, Wt2hi, Wt2lo);

    k_prep1<<<(N_NODES + 3) / 4, 256, 0, stream>>>(f8t, rp2, csr, agt);
    k_mfma1<<<N_PAD / 128, 256, 0, stream>>>(fbf, agt, Wt1hi, Wt1lo, b1, X2, h1c8);
    k_prep2<<<(N_NODES + 3) / 4, 256, 0, stream>>>(h1c8, rp2, csr, X2);
    k_mfma2<<<N_PAD / 128, 256, 0, stream>>>(X2, Wt2hi, Wt2lo, b2, h2c);

    k_weff<<<1, 256, 0, stream>>>(Wp1, bp1, Wp2, bp2, weff);
    k_readout<<<N_GRAPHS, 128, 0, stream>>>((const unsigned short*)h2c, gid, w_atom, b_atom, weff, out);
}

// Round 12
// 262.009 us; speedup vs baseline: 1.6836x; 1.1071x over previous
//
#include <hip/hip_runtime.h>

#define N_NODES 100000
#define N_PAD   100096   // 782 blocks * 128 rows
#define N_EDGES 1600000
#define N_GRAPHS 1024
#define F_IN 74
#define HID 100

#define KP1 160   // W1 layout: [self 0..73 | 0 | agg 80..153 | 0]; A from fbf(k<80)+agt(k>=80)
#define KP2 224   // [self h1 0..99 | agg 100..199 | 0 200..223]

#define FBF_LD 80    // bf16 feats rows (160B)
#define F8T_LD 80    // fp8 feats rows (80B stride -> always 2 cache lines)
#define AGT_LD 80    // bf16 agg1 rows (160B)
#define H1C8_LD 128  // fp8 h1 compact rows (128B)
#define H2_LD  100   // bf16 h2 rows (200B)

#define ZROW N_NODES                 // zero-row index for degree padding

#define NB ((N_NODES + 255) / 256)   // 391 dst-buckets of 256 nodes
#define BKCAP 8192                   // bbuf/csr slots per bucket (avg ~4092+pad, worst ~6200)
#define BIN_EPB 4096                 // edges per binning block
#define NBB ((N_EDGES + BIN_EPB - 1) / BIN_EPB)

typedef __attribute__((ext_vector_type(8))) short short8;
typedef __attribute__((ext_vector_type(4))) float f32x4;
typedef __attribute__((ext_vector_type(2))) float f32x2;

#if defined(__has_builtin)
#if __has_builtin(__builtin_amdgcn_cvt_pk_f32_fp8) && __has_builtin(__builtin_amdgcn_cvt_pk_fp8_f32)
#define HAVE_FP8 1
#endif
#endif

__device__ __forceinline__ unsigned short f2bf(float x) {
    union { float f; unsigned u; } c; c.f = x;
    unsigned u = c.u;
    unsigned r = (u + 0x7fffu + ((u >> 16) & 1u)) >> 16;
    return (unsigned short)r;
}
__device__ __forceinline__ float bf2f(unsigned short h) {
    union { unsigned u; float f; } c; c.u = ((unsigned)h) << 16;
    return c.f;
}
__device__ __forceinline__ float blo(unsigned w) { return bf2f((unsigned short)(w & 0xffffu)); }
__device__ __forceinline__ float bhi(unsigned w) { return bf2f((unsigned short)(w >> 16)); }
__device__ __forceinline__ unsigned bpack(float a, float b) {
    return (unsigned)f2bf(a) | ((unsigned)f2bf(b) << 16);
}
__device__ __forceinline__ void store8(void* p, unsigned lo, unsigned hi) {
    unsigned long long v = (unsigned long long)lo | ((unsigned long long)hi << 32);
    *(unsigned long long*)p = v;
}

// ---- fp8 e4m3 helpers (sign-aware) ----
__device__ __forceinline__ unsigned char enc_fp8_1(float v) {
#ifdef HAVE_FP8
    return (unsigned char)__builtin_amdgcn_cvt_pk_fp8_f32(v, 0.f, 0, false);
#else
    unsigned sgn = v < 0.f ? 0x80u : 0u;
    float m = fabsf(v);
    unsigned char mag;
    if (m < 0.015625f) {
        int q = (int)(m * 512.0f + 0.5f);
        mag = (unsigned char)(q > 7 ? 7 : q);
    } else {
        union { float f; unsigned u; } c; c.f = m;
        unsigned r = c.u + 0x7ffff + ((c.u >> 20) & 1u);
        int e = (int)(r >> 23) - 127;
        mag = (e > 8) ? (unsigned char)0x7e : (unsigned char)(((e + 7) << 3) | ((r >> 20) & 7u));
    }
    return (unsigned char)(sgn | mag);
#endif
}
__device__ __forceinline__ unsigned enc_fp8x4(float v0, float v1, float v2, float v3) {
#ifdef HAVE_FP8
    int r = __builtin_amdgcn_cvt_pk_fp8_f32(v0, v1, 0, false);
    r = __builtin_amdgcn_cvt_pk_fp8_f32(v2, v3, r, true);
    return (unsigned)r;
#else
    return (unsigned)enc_fp8_1(v0) | ((unsigned)enc_fp8_1(v1) << 8) |
           ((unsigned)enc_fp8_1(v2) << 16) | ((unsigned)enc_fp8_1(v3) << 24);
#endif
}
__device__ __forceinline__ void dec_fp8x4(unsigned w, float& x0, float& x1, float& x2, float& x3) {
#ifdef HAVE_FP8
    f32x2 lo = __builtin_amdgcn_cvt_pk_f32_fp8((int)w, false);
    f32x2 hi = __builtin_amdgcn_cvt_pk_f32_fp8((int)w, true);
    x0 = lo.x; x1 = lo.y; x2 = hi.x; x3 = hi.y;
#else
    auto d1 = [](unsigned b) -> float {
        float s = (b & 0x80u) ? -1.f : 1.f;
        b &= 0x7fu;
        if (b < 8) return s * (float)b * 0.001953125f;
        union { unsigned u; float f; } c;
        c.u = ((((b >> 3) & 15u) - 7 + 127) << 23) | ((b & 7u) << 20);
        return s * c.f;
    };
    x0 = d1(w & 0xffu); x1 = d1((w >> 8) & 0xffu);
    x2 = d1((w >> 16) & 0xffu); x3 = d1(w >> 24);
#endif
}

// ---------------- binned CSR fill (fixed-capacity buckets) ----------------
// bucket b = dst>>8; packed entry = (src<<8) | (dst&255); region [b*BKCAP, ...).

__global__ __launch_bounds__(256) void k_bin(const int* __restrict__ src,
                                             const int* __restrict__ dst,
                                             int* __restrict__ bucket_fill,
                                             unsigned* __restrict__ bbuf) {
    __shared__ int cnt[NB];
    __shared__ int base[NB];
    int t = threadIdx.x;
    for (int i = t; i < NB; i += 256) cnt[i] = 0;
    __syncthreads();
    int e0 = blockIdx.x * BIN_EPB;
    int e1 = e0 + BIN_EPB < N_EDGES ? e0 + BIN_EPB : N_EDGES;
    for (int e = e0 + t; e < e1; e += 256) {
        atomicAdd(&cnt[dst[e] >> 8], 1);
    }
    __syncthreads();
    for (int i = t; i < NB; i += 256) {
        int c = cnt[i];
        base[i] = c ? atomicAdd(&bucket_fill[i], c) : 0;
        cnt[i] = 0;
    }
    __syncthreads();
    for (int e = e0 + t; e < e1; e += 256) {
        int d = dst[e];
        int b = d >> 8;
        int pos = atomicAdd(&cnt[b], 1);
        bbuf[(size_t)b * BKCAP + base[b] + pos] = ((unsigned)src[e] << 8) | (unsigned)(d & 255);
    }
}

// scatter: builds rp2 (per-node start, start+deg) with deg padded to 8 in layout;
// pad slots point at ZROW (zero row). Then places csr entries.

__global__ __launch_bounds__(256) void k_scatter(const unsigned* __restrict__ bbuf,
                                                 const int* __restrict__ bucket_fill,
                                                 int2* __restrict__ rp2,
                                                 int* __restrict__ csr) {
    __shared__ int fc[256];
    __shared__ int ofs[256];
    __shared__ int wsum[4];
    int b = blockIdx.x, t = threadIdx.x;
    int nstart = b << 8;
    int base = b * BKCAP;
    int bend = base + bucket_fill[b];
    fc[t] = 0;
    __syncthreads();
    for (int i = base + t; i < bend; i += 256)
        atomicAdd(&fc[bbuf[i] & 255u], 1);
    __syncthreads();
    int d = fc[t];
    int dp = (d + 7) & ~7;               // padded degree (multiple of 8)
    int lane = t & 63, w = t >> 6;
    int inc = dp;
    #pragma unroll
    for (int o = 1; o < 64; o <<= 1) {
        int x = __shfl_up(inc, o, 64);
        if (lane >= o) inc += x;
    }
    if (lane == 63) wsum[w] = inc;
    __syncthreads();
    int woff = 0;
    for (int i = 0; i < w; ++i) woff += wsum[i];
    ofs[t] = base + woff + inc - dp;
    __syncthreads();
    int node = nstart + t;
    int o0 = ofs[t];
    if (node < N_NODES) rp2[node] = make_int2(o0, o0 + d);
    // fill pad slots with zero-row index
    for (int i = o0 + d; i < o0 + dp; ++i) csr[i] = ZROW;
    fc[t] = 0;
    __syncthreads();
    for (int i = base + t; i < bend; i += 256) {
        unsigned p = bbuf[i];
        int dl = (int)(p & 255u);
        int pos = atomicAdd(&fc[dl], 1);
        csr[ofs[dl] + pos] = (int)(p >> 8);
    }
}

// ---------------- feats -> bf16 copy [N][80] + fp8 copy [N][80B]; zero rows at ZROW ----------------

__global__ void k_feats(const float* __restrict__ feats, short* __restrict__ fbf,
                        unsigned* __restrict__ f8t, unsigned* __restrict__ h1c8) {
    int idx = blockIdx.x * blockDim.x + threadIdx.x;  // 4-col group index
    if (idx < H1C8_LD / 4) h1c8[(size_t)ZROW * (H1C8_LD / 4) + idx] = 0u;  // h1c8 zero row
    if (idx >= (N_NODES + 1) * (F8T_LD / 4)) return;
    int n = idx / (F8T_LD / 4), g = idx - n * (F8T_LD / 4);
    int c0 = 4 * g;
    float v0 = 0.f, v1 = 0.f, v2 = 0.f, v3 = 0.f;
    if (n < N_NODES) {
        const float* r = feats + (size_t)n * F_IN;
        v0 = (c0 + 0 < F_IN) ? r[c0 + 0] : 0.f;
        v1 = (c0 + 1 < F_IN) ? r[c0 + 1] : 0.f;
        v2 = (c0 + 2 < F_IN) ? r[c0 + 2] : 0.f;
        v3 = (c0 + 3 < F_IN) ? r[c0 + 3] : 0.f;
    }
    unsigned* fb = (unsigned*)fbf + (size_t)n * (FBF_LD / 2) + 2 * g;
    fb[0] = bpack(v0, v1);
    fb[1] = bpack(v2, v3);
    f8t[idx] = enc_fp8x4(v0, v1, v2, v3);
}

// ---------------- Weight preconvert: Wt[col][k], bf16 hi/lo ----------------

template <int KP, int K1, int AGG0>
__global__ void k_wconv(const float* __restrict__ Ws, const float* __restrict__ Wn,
                        short* __restrict__ Whi, short* __restrict__ Wlo) {
    int idx = blockIdx.x * blockDim.x + threadIdx.x;
    if (idx >= 112 * KP) return;
    int col = idx / KP, k = idx - col * KP;
    float v = 0.f;
    if (col < HID) {
        if (k < K1) v = Ws[k * HID + col];
        else if (k >= AGG0 && k < AGG0 + K1) v = Wn[(k - AGG0) * HID + col];
    }
    unsigned short hi = f2bf(v);
    unsigned short lo = f2bf(v - bf2f(hi));
    Whi[idx] = (short)hi;
    Wlo[idx] = (short)lo;
}

// ---------------- prep1: agt[v] = mean-agg of fp8 neighbor feats (bf16 out, 80 cols) ----------------
// Padded uniform loop: 8 edges/iter, no branches; pad edges hit the zero row.

__global__ __launch_bounds__(256) void k_prep1(const unsigned char* __restrict__ f8t,
                        const int2* __restrict__ rp2, const int* __restrict__ csr,
                        short* __restrict__ agt) {
    int wid = threadIdx.x >> 6, lane = threadIdx.x & 63;
    int v = blockIdx.x * 4 + wid;
    if (v >= N_NODES) return;
    int h = lane >> 5, q = lane & 31;
    int2 se = rp2[v];
    int s = se.x, e = se.y;
    int deg = e - s;
    int pe = s + ((deg + 7) & ~7);
    float a0 = 0.f, a1 = 0.f, a2 = 0.f, a3 = 0.f;
    if (q < 19) {
        #pragma unroll 2
        for (int j = s; j < pe; j += 8) {
            unsigned w0 = *(const unsigned*)(f8t + (size_t)csr[j + h] * F8T_LD + q * 4);
            unsigned w1 = *(const unsigned*)(f8t + (size_t)csr[j + 2 + h] * F8T_LD + q * 4);
            unsigned w2 = *(const unsigned*)(f8t + (size_t)csr[j + 4 + h] * F8T_LD + q * 4);
            unsigned w3 = *(const unsigned*)(f8t + (size_t)csr[j + 6 + h] * F8T_LD + q * 4);
            float x0, x1, x2, x3;
            dec_fp8x4(w0, x0, x1, x2, x3); a0 += x0; a1 += x1; a2 += x2; a3 += x3;
            dec_fp8x4(w1, x0, x1, x2, x3); a0 += x0; a1 += x1; a2 += x2; a3 += x3;
            dec_fp8x4(w2, x0, x1, x2, x3); a0 += x0; a1 += x1; a2 += x2; a3 += x3;
            dec_fp8x4(w3, x0, x1, x2, x3); a0 += x0; a1 += x1; a2 += x2; a3 += x3;
        }
    }
    a0 += __shfl_xor(a0, 32, 64);
    a1 += __shfl_xor(a1, 32, 64);
    a2 += __shfl_xor(a2, 32, 64);
    a3 += __shfl_xor(a3, 32, 64);
    float inv = 1.0f / fmaxf((float)deg, 1.0f);
    if (h == 0 && q < 20) {  // shorts 4q..4q+3 (q=19 -> zeros)
        store8((char*)agt + (size_t)v * (AGT_LD * 2) + q * 8,
               bpack(a0 * inv, a1 * inv), bpack(a2 * inv, a3 * inv));
    }
}

// ---------------- prep2: X2[:,100..223] = [mean-agg fp8(h1) | 0] ----------------

__global__ __launch_bounds__(256) void k_prep2(const unsigned char* __restrict__ h1c8,
                        const int2* __restrict__ rp2, const int* __restrict__ csr,
                        short* __restrict__ X2) {
    int wid = threadIdx.x >> 6, lane = threadIdx.x & 63;
    int v = blockIdx.x * 4 + wid;
    if (v >= N_NODES) return;
    int h = lane >> 5, q = lane & 31;
    int2 se = rp2[v];
    int s = se.x, e = se.y;
    int deg = e - s;
    int pe = s + ((deg + 7) & ~7);
    float a0 = 0.f, a1 = 0.f, a2 = 0.f, a3 = 0.f;
    if (q < 25) {
        #pragma unroll 2
        for (int j = s; j < pe; j += 8) {
            unsigned w0 = *(const unsigned*)(h1c8 + (size_t)csr[j + h] * H1C8_LD + q * 4);
            unsigned w1 = *(const unsigned*)(h1c8 + (size_t)csr[j + 2 + h] * H1C8_LD + q * 4);
            unsigned w2 = *(const unsigned*)(h1c8 + (size_t)csr[j + 4 + h] * H1C8_LD + q * 4);
            unsigned w3 = *(const unsigned*)(h1c8 + (size_t)csr[j + 6 + h] * H1C8_LD + q * 4);
            float x0, x1, x2, x3;
            dec_fp8x4(w0, x0, x1, x2, x3); a0 += x0; a1 += x1; a2 += x2; a3 += x3;
            dec_fp8x4(w1, x0, x1, x2, x3); a0 += x0; a1 += x1; a2 += x2; a3 += x3;
            dec_fp8x4(w2, x0, x1, x2, x3); a0 += x0; a1 += x1; a2 += x2; a3 += x3;
            dec_fp8x4(w3, x0, x1, x2, x3); a0 += x0; a1 += x1; a2 += x2; a3 += x3;
        }
    }
    a0 += __shfl_xor(a0, 32, 64);
    a1 += __shfl_xor(a1, 32, 64);
    a2 += __shfl_xor(a2, 32, 64);
    a3 += __shfl_xor(a3, 32, 64);
    float inv = 1.0f / fmaxf((float)deg, 1.0f);
    char* Xw = (char*)X2 + (size_t)v * (KP2 * 2);           // 448B row
    if (h == 0 && q < 25) {                                  // agg: shorts 100+4q..100+4q+3
        store8(Xw + 200 + q * 8, bpack(a0 * inv, a1 * inv), bpack(a2 * inv, a3 * inv));
    }
    if (h == 1 && q < 6) {                                   // zeros: shorts 200..223
        store8(Xw + 400 + q * 8, 0u, 0u);
    }
}

// ---------------- mfma1: h1 = relu([fbf|agt] @ Wt1^T + b1) -> X2 self (bf16) + h1c8 (fp8) ----------------

__global__ __launch_bounds__(256) void k_mfma1(
    const short* __restrict__ fbf, const short* __restrict__ agt,
    const short* __restrict__ Wthi, const short* __restrict__ Wtlo,
    const float* __restrict__ bias,
    short* __restrict__ X2, unsigned char* __restrict__ h1c8) {
    int t = threadIdx.x;
    int wid = t >> 6, lane = t & 63;
    int quad = lane >> 4, lr = lane & 15;
    int rowbase = blockIdx.x * 128 + wid * 32;

    f32x4 acc[2][7];
    #pragma unroll
    for (int rf = 0; rf < 2; ++rf)
        #pragma unroll
        for (int n = 0; n < 7; ++n) acc[rf][n] = (f32x4){0.f, 0.f, 0.f, 0.f};

    #pragma unroll
    for (int c = 0; c < 5; ++c) {
        short8 ah[2], wh[7], wl[7];
        #pragma unroll
        for (int rf = 0; rf < 2; ++rf) {
            int row = rowbase + rf * 16 + lr;
            const short* p;
            if (c < 2) p = fbf + (size_t)row * FBF_LD + c * 32 + quad * 8;
            else if (c == 2) p = (quad < 2) ? fbf + (size_t)row * FBF_LD + 64 + quad * 8
                                            : agt + (size_t)row * AGT_LD + (quad - 2) * 8;
            else p = agt + (size_t)row * AGT_LD + (c - 3) * 32 + 16 + quad * 8;
            ah[rf] = *(const short8*)p;
        }
        #pragma unroll
        for (int n = 0; n < 7; ++n) {
            size_t off = (size_t)(n * 16 + lr) * KP1 + c * 32 + quad * 8;
            wh[n] = *(const short8*)(Wthi + off);
            wl[n] = *(const short8*)(Wtlo + off);
        }
        #pragma unroll
        for (int rf = 0; rf < 2; ++rf)
            #pragma unroll
            for (int n = 0; n < 7; ++n) {
                acc[rf][n] = __builtin_amdgcn_mfma_f32_16x16x32_bf16(ah[rf], wh[n], acc[rf][n], 0, 0, 0);
                acc[rf][n] = __builtin_amdgcn_mfma_f32_16x16x32_bf16(ah[rf], wl[n], acc[rf][n], 0, 0, 0);
            }
    }

    #pragma unroll
    for (int rf = 0; rf < 2; ++rf) {
        #pragma unroll
        for (int n = 0; n < 7; ++n) {
            int col = n * 16 + lr;
            if (col < HID) {
                float bv = bias[col];
                #pragma unroll
                for (int r = 0; r < 4; ++r) {
                    int row = rowbase + rf * 16 + quad * 4 + r;
                    if (row < N_NODES) {
                        float v = fmaxf(acc[rf][n][r] + bv, 0.f);
                        X2[(size_t)row * KP2 + col] = (short)f2bf(v);
                        h1c8[(size_t)row * H1C8_LD + col] = enc_fp8_1(v);
                    }
                }
            }
        }
    }
}

// ---------------- mfma2: h2 = relu(X2 @ Wt2^T + b2) -> bf16 [N][100] ----------------

__global__ __launch_bounds__(256) void k_mfma2(
    const short* __restrict__ X2,
    const short* __restrict__ Wthi, const short* __restrict__ Wtlo,
    const float* __restrict__ bias, short* __restrict__ h2c) {
    int t = threadIdx.x;
    int wid = t >> 6, lane = t & 63;
    int quad = lane >> 4, lr = lane & 15;
    int rowbase = blockIdx.x * 128 + wid * 32;

    f32x4 acc[2][7];
    #pragma unroll
    for (int rf = 0; rf < 2; ++rf)
        #pragma unroll
        for (int n = 0; n < 7; ++n) acc[rf][n] = (f32x4){0.f, 0.f, 0.f, 0.f};

    #pragma unroll
    for (int c = 0; c < 7; ++c) {
        short8 ah[2], wh[7], wl[7];
        #pragma unroll
        for (int rf = 0; rf < 2; ++rf) {
            size_t off = (size_t)(rowbase + rf * 16 + lr) * KP2 + c * 32 + quad * 8;
            ah[rf] = *(const short8*)(X2 + off);
        }
        #pragma unroll
        for (int n = 0; n < 7; ++n) {
            size_t off = (size_t)(n * 16 + lr) * KP2 + c * 32 + quad * 8;
            wh[n] = *(const short8*)(Wthi + off);
            wl[n] = *(const short8*)(Wtlo + off);
        }
        #pragma unroll
        for (int rf = 0; rf < 2; ++rf)
            #pragma unroll
            for (int n = 0; n < 7; ++n) {
                acc[rf][n] = __builtin_amdgcn_mfma_f32_16x16x32_bf16(ah[rf], wh[n], acc[rf][n], 0, 0, 0);
                acc[rf][n] = __builtin_amdgcn_mfma_f32_16x16x32_bf16(ah[rf], wl[n], acc[rf][n], 0, 0, 0);
            }
    }

    #pragma unroll
    for (int rf = 0; rf < 2; ++rf) {
        #pragma unroll
        for (int n = 0; n < 7; ++n) {
            int col = n * 16 + lr;
            if (col < HID) {
                float bv = bias[col];
                #pragma unroll
                for (int r = 0; r < 4; ++r) {
                    int row = rowbase + rf * 16 + quad * 4 + r;
                    if (row < N_NODES) {
                        float v = fmaxf(acc[rf][n][r] + bv, 0.f);
                        h2c[(size_t)row * H2_LD + col] = (short)f2bf(v);
                    }
                }
            }
        }
    }
}

// ---------------- Collapsed predictor head: w_eff[200], b_eff ----------------

__global__ void k_weff(const float* __restrict__ Wp1, const float* __restrict__ bp1,
                       const float* __restrict__ Wp2, const float* __restrict__ bp2,
                       float* __restrict__ weff) {
    int t = threadIdx.x;
    if (t < 200) {
        float s = 0.f;
        for (int k = 0; k < 64; ++k) s += Wp1[t * 64 + k] * Wp2[k];
        weff[t] = s;
    } else if (t == 200) {
        float s = bp2[0];
        for (int k = 0; k < 64; ++k) s += bp1[k] * Wp2[k];
        weff[200] = s;
    }
}

// ---------------- Readout (bf16 h2, uint loads): per-graph weighted sum + max, fused head ----------------

__global__ __launch_bounds__(128) void k_readout(
    const unsigned short* __restrict__ h2c, const int* __restrict__ graph_ids,
    const float* __restrict__ w_atom, const float* __restrict__ b_atom,
    const float* __restrict__ weff, float* __restrict__ out) {
    int g = blockIdx.x;
    int t = threadIdx.x, lane = t & 63, w = t >> 6;

    int s_, e_;
    {
        int l = 0, r = N_NODES;
        while (l < r) { int m = (l + r) >> 1; if (graph_ids[m] < g) l = m + 1; else r = m; }
        s_ = l;
        l = s_; r = N_NODES;
        while (l < r) { int m = (l + r) >> 1; if (graph_ids[m] < g + 1) l = m + 1; else r = m; }
        e_ = l;
    }

    float ba = b_atom[0];
    float wa0 = 0.f, wa1 = 0.f;
    if (lane < 50) {
        float2 wv = *(const float2*)&w_atom[2 * lane];
        wa0 = wv.x; wa1 = wv.y;
    }
    float sum0 = 0.f, sum1 = 0.f, mx0 = 0.f, mx1 = 0.f;  // h >= 0 (relu)
    for (int i = s_ + w; i < e_; i += 2) {
        float v0 = 0.f, v1 = 0.f;
        if (lane < 50) {
            unsigned wv = *(const unsigned*)(h2c + (size_t)i * H2_LD + 2 * lane);
            v0 = blo(wv); v1 = bhi(wv);
        }
        float p = v0 * wa0 + v1 * wa1;
        #pragma unroll
        for (int off = 32; off; off >>= 1) p += __shfl_xor(p, off, 64);
        float wt = 1.f / (1.f + __expf(-(p + ba)));
        sum0 += v0 * wt;
        sum1 += v1 * wt;
        mx0 = fmaxf(mx0, v0);
        mx1 = fmaxf(mx1, v1);
    }

    __shared__ float ssum[2][HID];
    __shared__ float smx[2][HID];
    if (lane < 50) {
        ssum[w][2 * lane] = sum0;
        ssum[w][2 * lane + 1] = sum1;
        smx[w][2 * lane] = mx0;
        smx[w][2 * lane + 1] = mx1;
    }
    __syncthreads();

    float contrib = 0.f;
    if (t < HID) {
        float sumf = ssum[0][t] + ssum[1][t];
        float mxf = fmaxf(smx[0][t], smx[1][t]);
        contrib = sumf * weff[t] + mxf * weff[HID + t];
    }
    #pragma unroll
    for (int off = 32; off; off >>= 1) contrib += __shfl_xor(contrib, off, 64);
    __shared__ float red[2];
    if (lane == 0) red[w] = contrib;
    __syncthreads();
    if (t == 0) out[g] = red[0] + red[1] + weff[200];
}

// ---------------- launch ----------------

extern "C" void kernel_launch(void* const* d_in, const int* in_sizes, int n_in,
                              void* d_out, int out_size, void* d_ws, size_t ws_size,
                              hipStream_t stream) {
    const float* node_feats = (const float*)d_in[0];
    const int* src = (const int*)d_in[1];
    const int* dst = (const int*)d_in[2];
    const int* gid = (const int*)d_in[3];
    const float* Ws1 = (const float*)d_in[5];
    const float* Wn1 = (const float*)d_in[6];
    const float* b1 = (const float*)d_in[7];
    const float* Ws2 = (const float*)d_in[8];
    const float* Wn2 = (const float*)d_in[9];
    const float* b2 = (const float*)d_in[10];
    const float* w_atom = (const float*)d_in[11];
    const float* b_atom = (const float*)d_in[12];
    const float* Wp1 = (const float*)d_in[13];
    const float* bp1 = (const float*)d_in[14];
    const float* Wp2 = (const float*)d_in[15];
    const float* bp2 = (const float*)d_in[16];
    float* out = (float*)d_out;

    char* ws = (char*)d_ws;
    size_t off = 0;
    auto alloc = [&](size_t bytes) -> void* {
        void* p = (void*)(ws + off);
        off += (bytes + 255) & ~(size_t)255;
        return p;
    };
    int2* rp2 = (int2*)alloc((size_t)N_NODES * sizeof(int2));
    int* bucket_fill = (int*)alloc(NB * sizeof(int));
    int* csr = (int*)alloc((size_t)NB * BKCAP * sizeof(int));                 // 12.8 MB
    unsigned* bbuf = (unsigned*)alloc((size_t)NB * BKCAP * sizeof(unsigned)); // 12.8 MB
    short* fbf = (short*)alloc((size_t)(N_PAD + 1) * FBF_LD * sizeof(short)); // 16 MB
    unsigned char* f8t = (unsigned char*)alloc((size_t)(N_PAD + 1) * F8T_LD); // 8 MB
    short* agt = (short*)alloc((size_t)N_PAD * AGT_LD * sizeof(short));       // 16 MB
    short* X2 = (short*)alloc((size_t)N_PAD * KP2 * sizeof(short));           // 44.8 MB
    unsigned char* h1c8 = (unsigned char*)alloc((size_t)(N_NODES + 1) * H1C8_LD); // 12.8 MB
    short* h2c = (short*)alloc((size_t)N_NODES * H2_LD * sizeof(short));      // 20 MB
    short* Wt1hi = (short*)alloc(112 * KP1 * sizeof(short));
    short* Wt1lo = (short*)alloc(112 * KP1 * sizeof(short));
    short* Wt2hi = (short*)alloc(112 * KP2 * sizeof(short));
    short* Wt2lo = (short*)alloc(112 * KP2 * sizeof(short));
    float* weff = (float*)alloc(256 * sizeof(float));

    hipMemsetAsync(bucket_fill, 0, NB * sizeof(int), stream);

    k_bin<<<NBB, 256, 0, stream>>>(src, dst, bucket_fill, bbuf);
    k_scatter<<<NB, 256, 0, stream>>>(bbuf, bucket_fill, rp2, csr);

    k_feats<<<((N_NODES + 1) * (F8T_LD / 4) + 255) / 256, 256, 0, stream>>>(
        node_feats, fbf, (unsigned*)f8t, (unsigned*)h1c8);
    k_wconv<KP1, F_IN, 80><<<(112 * KP1 + 255) / 256, 256, 0, stream>>>(Ws1, Wn1, Wt1hi, Wt1lo);
    k_wconv<KP2, HID, 100><<<(112 * KP2 + 255) / 256, 256, 0, stream>>>(Ws2, Wn2, Wt2hi, Wt2lo);

    k_prep1<<<(N_NODES + 3) / 4, 256, 0, stream>>>(f8t, rp2, csr, agt);
    k_mfma1<<<N_PAD / 128, 256, 0, stream>>>(fbf, agt, Wt1hi, Wt1lo, b1, X2, h1c8);
    k_prep2<<<(N_NODES + 3) / 4, 256, 0, stream>>>(h1c8, rp2, csr, X2);
    k_mfma2<<<N_PAD / 128, 256, 0, stream>>>(X2, Wt2hi, Wt2lo, b2, h2c);

    k_weff<<<1, 256, 0, stream>>>(Wp1, bp1, Wp2, bp2, weff);
    k_readout<<<N_GRAPHS, 128, 0, stream>>>((const unsigned short*)h2c, gid, w_atom, b_atom, weff, out);
}